// Round 9
// baseline (310.915 us; speedup 1.0000x reference)
//
#include <hip/hip_runtime.h>
#include <math.h>

namespace {
constexpr int S  = 256;
constexpr int NT = 256;
constexpr float SCALE = 0.0625f;  // 1/sqrt(256)
}

typedef __bf16 bf16x4 __attribute__((ext_vector_type(4)));
typedef __bf16 bf16x8 __attribute__((ext_vector_type(8)));
typedef float  f32x4  __attribute__((ext_vector_type(4)));

#define MFMA(a, b, c) __builtin_amdgcn_mfma_f32_16x16x32_bf16((a), (b), (c), 0, 0, 0)

struct VF3 { bf16x8 h, l, ll; };
struct VF2 { bf16x8 h, l; };

// ===== prep: V^T 3-way bf16 split, FRAGMENT-PACKED =====
// packed idx (per bh): tc*8192 + j*512 + lane*8 + e
//   where lane = l4*16 + l15, d = j*16+l15, t = tc*32 + l4*8 + e
// One block handles one (bh, tc): 32 t-rows x 256 d.
__global__ __launch_bounds__(NT) void vsplit_kernel(
    const float* __restrict__ v,
    __bf16* __restrict__ vth, __bf16* __restrict__ vtl, __bf16* __restrict__ vtll)
{
    __shared__ float tile[32][257];     // [t_local][d]
    const int bh = blockIdx.x >> 3;
    const int tc = blockIdx.x & 7;
    const int tid = threadIdx.x;

    const float* vb = v + (size_t)bh * S * S + (size_t)tc * 32 * S;
    // stage 32x256 fp32 chunk, coalesced float4
    {
        const int c4 = (tid & 63) * 4;
        const int r  = tid >> 6;
        #pragma unroll
        for (int rr = 0; rr < 8; ++rr) {
            const int row = rr * 4 + r;
            const float4 f = *(const float4*)&vb[(size_t)row * S + c4];
            tile[row][c4 + 0] = f.x; tile[row][c4 + 1] = f.y;
            tile[row][c4 + 2] = f.z; tile[row][c4 + 3] = f.w;
        }
    }
    __syncthreads();

    const size_t obase = (size_t)bh * S * S + (size_t)tc * 8192;
    #pragma unroll
    for (int it = 0; it < 4; ++it) {
        const int id  = it * 256 + tid;      // 0..1023
        const int j   = id >> 6;
        const int l4  = (id >> 4) & 3;
        const int l15 = id & 15;
        const int d   = j * 16 + l15;
        const int t0  = l4 * 8;
        bf16x8 hv, lv, llv;
        #pragma unroll
        for (int e = 0; e < 8; ++e) {
            const float x = tile[t0 + e][d];
            const __bf16 hi = (__bf16)x;
            const float  hf = (float)hi;
            const __bf16 lo = (__bf16)(x - hf);
            const float  lf = (float)lo;
            hv[e] = hi; lv[e] = lo; llv[e] = (__bf16)(x - hf - lf);
        }
        const size_t oi = obase + (size_t)id * 8;
        *(bf16x8*)&vth[oi]  = hv;
        *(bf16x8*)&vtl[oi]  = lv;
        *(bf16x8*)&vtll[oi] = llv;
    }
}

// ===== QKT: r = (scale*Q) K^T, 3-pass split MFMA -> packed r_hi/r_lo =====
// packed A idx (per bh): sb*4096 + tc*512 + lane*8 + e
//   where s = sb*16 + l15, t = tc*32 + l4*8 + e
__global__ __launch_bounds__(NT) void qkt_kernel(
    const float* __restrict__ q, const float* __restrict__ k,
    __bf16* __restrict__ r_hi, __bf16* __restrict__ r_lo, int swz)
{
    __shared__ __align__(16) __bf16 kh[256 * 40];
    __shared__ __align__(16) __bf16 kl[256 * 40];

    const int tid = threadIdx.x;
    const int w = tid >> 6, l = tid & 63, l15 = l & 15, l4 = l >> 4;

    int L = blockIdx.x;
    if (swz) L = (blockIdx.x & 7) * ((int)gridDim.x >> 3) + (blockIdx.x >> 3);
    const int bh = L >> 2;
    const int s0 = (L & 3) << 6;

    const float* qb = q + ((size_t)bh << 16);
    const float* kb = k + ((size_t)bh << 16);

    bf16x8 qh[8], ql[8];
    {
        const float* qr = qb + (size_t)(s0 + 16 * w + l15) * S;
        #pragma unroll
        for (int kc = 0; kc < 8; ++kc) {
            const float4 f0 = *(const float4*)&qr[kc * 32 + l4 * 8];
            const float4 f1 = *(const float4*)&qr[kc * 32 + l4 * 8 + 4];
            const float xs[8] = {f0.x, f0.y, f0.z, f0.w, f1.x, f1.y, f1.z, f1.w};
            bf16x8 hv, lv;
            #pragma unroll
            for (int e = 0; e < 8; ++e) {
                const float x = xs[e] * SCALE;
                const __bf16 hi = (__bf16)x;
                hv[e] = hi; lv[e] = (__bf16)(x - (float)hi);
            }
            qh[kc] = hv; ql[kc] = lv;
        }
    }

    f32x4 acc[16];
    #pragma unroll
    for (int j = 0; j < 16; ++j) acc[j] = (f32x4){0.f, 0.f, 0.f, 0.f};

    #pragma unroll
    for (int kc = 0; kc < 8; ++kc) {
        #pragma unroll
        for (int pass = 0; pass < 8; ++pass) {
            const int row = pass * 32 + (tid >> 3);
            const int sub = tid & 7;
            const float4 f = *(const float4*)&kb[(size_t)row * S + kc * 32 + sub * 4];
            const float xs[4] = {f.x, f.y, f.z, f.w};
            bf16x4 hv, lv;
            #pragma unroll
            for (int e = 0; e < 4; ++e) {
                const __bf16 hi = (__bf16)xs[e];
                hv[e] = hi; lv[e] = (__bf16)(xs[e] - (float)hi);
            }
            *(bf16x4*)&kh[row * 40 + sub * 4] = hv;
            *(bf16x4*)&kl[row * 40 + sub * 4] = lv;
        }
        __syncthreads();
        #pragma unroll
        for (int j = 0; j < 16; ++j) {
            const int bo = (j * 16 + l15) * 40 + l4 * 8;
            const bf16x8 khf = *(const bf16x8*)&kh[bo];
            const bf16x8 klf = *(const bf16x8*)&kl[bo];
            acc[j] = MFMA(qh[kc], khf, acc[j]);
            acc[j] = MFMA(qh[kc], klf, acc[j]);
            acc[j] = MFMA(ql[kc], khf, acc[j]);
        }
        __syncthreads();
    }

    // packed epilogue: value r[s0+16w+l4*4+rr][j*16+l15]
    __bf16* rh_pk = r_hi + ((size_t)bh << 16);
    __bf16* rl_pk = r_lo + ((size_t)bh << 16);
    const int sb = (s0 >> 4) + w;
    #pragma unroll
    for (int j = 0; j < 16; ++j) {
        const int tcj = j >> 1;
        const int l4t = ((j & 1) << 1) + (l15 >> 3);
        const int et  = l15 & 7;
        #pragma unroll
        for (int rr = 0; rr < 4; ++rr) {
            const int r15 = l4 * 4 + rr;
            const float rv = acc[j][rr];
            const __bf16 hi = (__bf16)rv;
            const int idx = sb * 4096 + tcj * 512 + l4t * 128 + r15 * 8 + et;
            rh_pk[idx] = hi;
            rl_pk[idx] = (__bf16)(rv - (float)hi);
        }
    }
}

// ===== attn2: (mask + r)@V -> softmax -> P@V, packed coalesced loads =====
#define MQ2(Q, BUF, RH, RL, MF)                                         \
    _Pragma("unroll")                                                   \
    for (int jj = 0; jj < 4; ++jj) {                                    \
        acc2[(Q)*4+jj] = MFMA(MF, BUF[jj].h,  acc2[(Q)*4+jj]);          \
        acc2[(Q)*4+jj] = MFMA(MF, BUF[jj].l,  acc2[(Q)*4+jj]);          \
        acc2[(Q)*4+jj] = MFMA(MF, BUF[jj].ll, acc2[(Q)*4+jj]);          \
        acc2[(Q)*4+jj] = MFMA(RH, BUF[jj].h,  acc2[(Q)*4+jj]);          \
        acc2[(Q)*4+jj] = MFMA(RH, BUF[jj].l,  acc2[(Q)*4+jj]);          \
        acc2[(Q)*4+jj] = MFMA(RL, BUF[jj].h,  acc2[(Q)*4+jj]);          \
    }

#define MQ3(Q, BUF, PA)                                                 \
    _Pragma("unroll")                                                   \
    for (int jj = 0; jj < 4; ++jj) {                                    \
        acc3[(Q)*4+jj] = MFMA(PA, BUF[jj].h, acc3[(Q)*4+jj]);           \
        acc3[(Q)*4+jj] = MFMA(PA, BUF[jj].l, acc3[(Q)*4+jj]);           \
    }

__global__ __launch_bounds__(NT, 2) void attn2_kernel(
    const float* __restrict__ mask,
    const __bf16* __restrict__ r_hi, const __bf16* __restrict__ r_lo,
    const __bf16* __restrict__ vth, const __bf16* __restrict__ vtl,
    const __bf16* __restrict__ vtll,
    float* __restrict__ out, int H, int swz)
{
    __shared__ __align__(16) __bf16 pT[64 * 256];   // swizzled P tile (32 KB)

    const int tid = threadIdx.x;
    const int w = tid >> 6, l = tid & 63, l15 = l & 15, l4 = l >> 4;

    int L = blockIdx.x;
    if (swz) L = (blockIdx.x & 7) * ((int)gridDim.x >> 3) + (blockIdx.x >> 3);
    const int bh = L >> 2;
    const int s0 = (L & 3) << 6;
    const int h  = bh % H;

    const size_t hb = (size_t)bh << 16;
    const float* mbase = mask + ((size_t)h << 16);

    const int sb = (s0 >> 4) + w;
    const __bf16* rh_p = r_hi + hb + (size_t)sb * 4096;   // + tc*512 + l*8
    const __bf16* rl_p = r_lo + hb + (size_t)sb * 4096;
    const float*  m_p  = mbase + (size_t)(s0 + 16 * w + l15) * S;

    // ---- phase 2: acc2 = (mask + r) @ V, register double-buffered ----
    f32x4 acc2[16];
    #pragma unroll
    for (int j = 0; j < 16; ++j) acc2[j] = (f32x4){0.f, 0.f, 0.f, 0.f};

    VF3 b0[4], b1[4];

    auto LDV3 = [&](int tc, int q, VF3* buf) {
        #pragma unroll
        for (int jj = 0; jj < 4; ++jj) {
            const int j = q * 4 + jj;
            const size_t vo = hb + (size_t)tc * 8192 + (size_t)j * 512 + (size_t)l * 8;
            buf[jj].h  = *(const bf16x8*)&vth[vo];
            buf[jj].l  = *(const bf16x8*)&vtl[vo];
            buf[jj].ll = *(const bf16x8*)&vtll[vo];
        }
    };

    LDV3(0, 0, b0);
    #pragma unroll
    for (int tc = 0; tc < 8; ++tc) {
        const bf16x8 rh = *(const bf16x8*)&rh_p[tc * 512 + l * 8];
        const bf16x8 rl = *(const bf16x8*)&rl_p[tc * 512 + l * 8];
        const int ko = tc * 32 + l4 * 8;
        const float4 m0 = *(const float4*)&m_p[ko];
        const float4 m1 = *(const float4*)&m_p[ko + 4];
        bf16x8 mf;
        mf[0] = (__bf16)m0.x; mf[1] = (__bf16)m0.y;
        mf[2] = (__bf16)m0.z; mf[3] = (__bf16)m0.w;
        mf[4] = (__bf16)m1.x; mf[5] = (__bf16)m1.y;
        mf[6] = (__bf16)m1.z; mf[7] = (__bf16)m1.w;

        LDV3(tc, 1, b1);
        MQ2(0, b0, rh, rl, mf)
        LDV3(tc, 2, b0);
        MQ2(1, b1, rh, rl, mf)
        LDV3(tc, 3, b1);
        MQ2(2, b0, rh, rl, mf)
        LDV3(tc < 7 ? tc + 1 : 7, 0, b0);
        MQ2(3, b1, rh, rl, mf)
    }

    // ---- masked fill + row softmax (in-register, per 16-lane group) ----
    #pragma unroll
    for (int rr = 0; rr < 4; ++rr) {
        const int srow = 16 * w + l4 * 4 + rr;
        const float* mrow = mbase + (size_t)(s0 + srow) * S;
        float mx = -3.4e38f;
        #pragma unroll
        for (int j = 0; j < 16; ++j) {
            const float mval = mrow[j * 16 + l15];
            const float a = (mval == 0.0f) ? -1e9f : acc2[j][rr];
            acc2[j][rr] = a;
            mx = fmaxf(mx, a);
        }
        #pragma unroll
        for (int off = 1; off < 16; off <<= 1)
            mx = fmaxf(mx, __shfl_xor(mx, off, 64));
        float sm = 0.f;
        #pragma unroll
        for (int j = 0; j < 16; ++j) {
            const float e = __expf(acc2[j][rr] - mx);
            acc2[j][rr] = e;
            sm += e;
        }
        #pragma unroll
        for (int off = 1; off < 16; off <<= 1)
            sm += __shfl_xor(sm, off, 64);
        const float inv = 1.0f / sm;
        #pragma unroll
        for (int j = 0; j < 16; ++j) {
            const int t = j * 16 + l15;
            pT[((srow << 8) + t) ^ ((srow & 7) << 3)] = (__bf16)(acc2[j][rr] * inv);
        }
    }
    __syncthreads();

    // ---- phase 3: out = P @ V, register double-buffered ----
    f32x4 acc3[16];
    #pragma unroll
    for (int j = 0; j < 16; ++j) acc3[j] = (f32x4){0.f, 0.f, 0.f, 0.f};

    VF2 c0[4], c1[4];
    auto LDV2 = [&](int tc, int q, VF2* buf) {
        #pragma unroll
        for (int jj = 0; jj < 4; ++jj) {
            const int j = q * 4 + jj;
            const size_t vo = hb + (size_t)tc * 8192 + (size_t)j * 512 + (size_t)l * 8;
            buf[jj].h = *(const bf16x8*)&vth[vo];
            buf[jj].l = *(const bf16x8*)&vtl[vo];
        }
    };

    const int prow = 16 * w + l15;
    LDV2(0, 0, c0);
    #pragma unroll
    for (int tc = 0; tc < 8; ++tc) {
        const int pb = ((prow << 8) + tc * 32 + l4 * 8) ^ ((prow & 7) << 3);
        const bf16x8 pa = *(const bf16x8*)&pT[pb];

        LDV2(tc, 1, c1);
        MQ3(0, c0, pa)
        LDV2(tc, 2, c0);
        MQ3(1, c1, pa)
        LDV2(tc, 3, c1);
        MQ3(2, c0, pa)
        LDV2(tc < 7 ? tc + 1 : 7, 0, c0);
        MQ3(3, c1, pa)
    }

    float* ob = out + hb + (size_t)s0 * S;
    #pragma unroll
    for (int j = 0; j < 16; ++j) {
        #pragma unroll
        for (int rr = 0; rr < 4; ++rr)
            ob[(size_t)(16 * w + l4 * 4 + rr) * S + j * 16 + l15] = acc3[j][rr];
    }
}

// ================= fallback: fp32 path (verified round 2) =================
__global__ __launch_bounds__(NT) void transpose_k_kernel(
    const float* __restrict__ k, float* __restrict__ kt)
{
    __shared__ float tile[64][65];
    const int tileIdx = blockIdx.x & 15;
    const int bh      = blockIdx.x >> 4;
    const int ti = (tileIdx >> 2) * 64;
    const int tj = (tileIdx & 3) * 64;
    const float* kb = k  + (size_t)bh * S * S;
    float*      ktb = kt + (size_t)bh * S * S;
    const int c  = threadIdx.x & 63;
    const int r4 = threadIdx.x >> 6;
    #pragma unroll
    for (int rr = 0; rr < 64; rr += 4)
        tile[rr + r4][c] = kb[(size_t)(ti + rr + r4) * S + tj + c];
    __syncthreads();
    #pragma unroll
    for (int rr = 0; rr < 64; rr += 4)
        ktb[(size_t)(tj + rr + r4) * S + ti + c] = tile[c][rr + r4];
}

template <int RPB>
__global__ __launch_bounds__(NT) void fused_attn_rpb(
    const float* __restrict__ q, const float* __restrict__ kt,
    const float* __restrict__ v, const float* __restrict__ mask,
    float* __restrict__ out, int nbh, int H, int swizzle)
{
    __shared__ float qT[S][RPB];
    __shared__ float sT[S][RPB];
    __shared__ float redbuf[4][RPB];

    const int tid = threadIdx.x;
    constexpr int NRB = S / RPB;
    int bh, rb;
    if (swizzle) {
        const int xcd  = blockIdx.x & 7;
        const int slot = blockIdx.x >> 3;
        const int hpx  = nbh >> 3;
        bh = xcd * hpx + (slot % hpx);
        rb = slot / hpx;
    } else {
        bh = blockIdx.x / NRB;
        rb = blockIdx.x % NRB;
    }
    const int h  = bh % H;
    const int s0 = rb * RPB;

    const float* qb  = q    + (size_t)bh * S * S;
    const float* ktb = kt   + (size_t)bh * S * S;
    const float* vb  = v    + (size_t)bh * S * S;
    const float* mb  = mask + (size_t)h  * S * S + (size_t)s0 * S;
    float*       ob  = out  + (size_t)bh * S * S + (size_t)s0 * S;

    #pragma unroll
    for (int si = 0; si < RPB; ++si)
        qT[tid][si] = qb[(size_t)(s0 + si) * S + tid];
    __syncthreads();

    {
        float acc[RPB];
        #pragma unroll
        for (int si = 0; si < RPB; ++si) acc[si] = 0.f;
        #pragma unroll 4
        for (int i = 0; i < S; ++i) {
            const float kv = ktb[(size_t)i * S + tid];
            #pragma unroll
            for (int si4 = 0; si4 < RPB; si4 += 4) {
                const float4 qa = *reinterpret_cast<const float4*>(&qT[i][si4]);
                acc[si4+0] = fmaf(qa.x, kv, acc[si4+0]);
                acc[si4+1] = fmaf(qa.y, kv, acc[si4+1]);
                acc[si4+2] = fmaf(qa.z, kv, acc[si4+2]);
                acc[si4+3] = fmaf(qa.w, kv, acc[si4+3]);
            }
        }
        #pragma unroll
        for (int si4 = 0; si4 < RPB; si4 += 4) {
            float4 t4;
            t4.x = fmaf(acc[si4+0], SCALE, mb[(size_t)(si4+0)*S + tid]);
            t4.y = fmaf(acc[si4+1], SCALE, mb[(size_t)(si4+1)*S + tid]);
            t4.z = fmaf(acc[si4+2], SCALE, mb[(size_t)(si4+2)*S + tid]);
            t4.w = fmaf(acc[si4+3], SCALE, mb[(size_t)(si4+3)*S + tid]);
            *reinterpret_cast<float4*>(&sT[tid][si4]) = t4;
        }
    }
    __syncthreads();

    float a1[RPB];
    #pragma unroll
    for (int si = 0; si < RPB; ++si) a1[si] = 0.f;
    #pragma unroll 2
    for (int t = 0; t < S; ++t) {
        const float vv = vb[(size_t)t * S + tid];
        #pragma unroll
        for (int si4 = 0; si4 < RPB; si4 += 4) {
            const float4 pa = *reinterpret_cast<const float4*>(&sT[t][si4]);
            a1[si4+0] = fmaf(pa.x, vv, a1[si4+0]);
            a1[si4+1] = fmaf(pa.y, vv, a1[si4+1]);
            a1[si4+2] = fmaf(pa.z, vv, a1[si4+2]);
            a1[si4+3] = fmaf(pa.w, vv, a1[si4+3]);
        }
    }
    #pragma unroll
    for (int si = 0; si < RPB; ++si)
        if (mb[(size_t)si * S + tid] == 0.0f) a1[si] = -1e9f;

    const int lane = tid & 63;
    const int wv   = tid >> 6;
    #pragma unroll
    for (int si = 0; si < RPB; ++si) {
        float m = a1[si];
        #pragma unroll
        for (int off = 32; off > 0; off >>= 1)
            m = fmaxf(m, __shfl_down(m, off, 64));
        if (lane == 0) redbuf[wv][si] = m;
    }
    __syncthreads();
    float e[RPB];
    #pragma unroll
    for (int si = 0; si < RPB; ++si) {
        const float m = fmaxf(fmaxf(redbuf[0][si], redbuf[1][si]),
                              fmaxf(redbuf[2][si], redbuf[3][si]));
        e[si] = __expf(a1[si] - m);
    }
    __syncthreads();
    #pragma unroll
    for (int si = 0; si < RPB; ++si) {
        float sm = e[si];
        #pragma unroll
        for (int off = 32; off > 0; off >>= 1)
            sm += __shfl_down(sm, off, 64);
        if (lane == 0) redbuf[wv][si] = sm;
    }
    __syncthreads();
    #pragma unroll
    for (int si4 = 0; si4 < RPB; si4 += 4) {
        float4 t4;
        #pragma unroll
        for (int jj = 0; jj < 4; ++jj) {
            const int si = si4 + jj;
            const float sm = redbuf[0][si] + redbuf[1][si] +
                             redbuf[2][si] + redbuf[3][si];
            (&t4.x)[jj] = e[si] / sm;
        }
        *reinterpret_cast<float4*>(&sT[tid][si4]) = t4;
    }
    __syncthreads();

    float o[RPB];
    #pragma unroll
    for (int si = 0; si < RPB; ++si) o[si] = 0.f;
    #pragma unroll 2
    for (int t = 0; t < S; ++t) {
        const float vv = vb[(size_t)t * S + tid];
        #pragma unroll
        for (int si4 = 0; si4 < RPB; si4 += 4) {
            const float4 pa = *reinterpret_cast<const float4*>(&sT[t][si4]);
            o[si4+0] = fmaf(pa.x, vv, o[si4+0]);
            o[si4+1] = fmaf(pa.y, vv, o[si4+1]);
            o[si4+2] = fmaf(pa.z, vv, o[si4+2]);
            o[si4+3] = fmaf(pa.w, vv, o[si4+3]);
        }
    }
    #pragma unroll
    for (int si = 0; si < RPB; ++si)
        ob[(size_t)si * S + tid] = o[si];
}

extern "C" void kernel_launch(void* const* d_in, const int* in_sizes, int n_in,
                              void* d_out, int out_size, void* d_ws, size_t ws_size,
                              hipStream_t stream) {
    const float* q    = (const float*)d_in[0];
    const float* k    = (const float*)d_in[1];
    const float* v    = (const float*)d_in[2];
    const float* mask = (const float*)d_in[3];
    float* out = (float*)d_out;

    const int nbh = in_sizes[0] / (S * S);   // B*H
    const int H   = in_sizes[3] / (S * S);   // heads
    const size_t he = (size_t)nbh * S * S;
    const size_t need = he * sizeof(__bf16) * 5;   // vth,vtl,vtll,r_hi,r_lo
    const size_t kt_bytes = he * sizeof(float);

    if (ws_size >= need) {
        __bf16* vth  = (__bf16*)d_ws;
        __bf16* vtl  = vth + he;
        __bf16* vtll = vtl + he;
        __bf16* rhi  = vtll + he;
        __bf16* rlo  = rhi + he;
        const int nblk = nbh * 4;
        const int swz = (nblk % 8 == 0) ? 1 : 0;
        vsplit_kernel<<<dim3(nbh * 8), NT, 0, stream>>>(v, vth, vtl, vtll);
        qkt_kernel<<<dim3(nblk), NT, 0, stream>>>(q, k, rhi, rlo, swz);
        attn2_kernel<<<dim3(nblk), NT, 0, stream>>>(
            mask, rhi, rlo, vth, vtl, vtll, out, H, swz);
    } else if (ws_size >= kt_bytes) {
        float* kt = (float*)d_ws;
        transpose_k_kernel<<<dim3(nbh * 16), NT, 0, stream>>>(k, kt);
        constexpr int RPB = 16;
        const int grid = nbh * (S / RPB);
        const int swz = (nbh % 8 == 0) ? 1 : 0;
        fused_attn_rpb<RPB><<<dim3(grid), NT, 0, stream>>>(
            q, kt, v, mask, out, nbh, H, swz);
    }
}

// Round 10
// 115.543 us; speedup vs baseline: 2.6909x; 2.6909x over previous
//
#include <hip/hip_runtime.h>
#include <math.h>

namespace {
constexpr int S  = 256;
constexpr int NT = 256;
constexpr float SCALE = 0.0625f;  // 1/sqrt(256)
}

typedef __bf16 bf16x4 __attribute__((ext_vector_type(4)));
typedef __bf16 bf16x8 __attribute__((ext_vector_type(8)));
typedef float  f32x4  __attribute__((ext_vector_type(4)));

#define MFMA(a, b, c) __builtin_amdgcn_mfma_f32_16x16x32_bf16((a), (b), (c), 0, 0, 0)

// ===== prep: V^T 3-way bf16 split, FRAGMENT-PACKED (verified round 9) =====
// packed idx (per bh): tc*8192 + j*512 + lane*8 + e
//   where d = j*16 + (lane&15), t = tc*32 + (lane>>4)*8 + e
__global__ __launch_bounds__(NT) void vsplit_kernel(
    const float* __restrict__ v,
    __bf16* __restrict__ vth, __bf16* __restrict__ vtl, __bf16* __restrict__ vtll)
{
    __shared__ float tile[32][257];     // [t_local][d]
    const int bh = blockIdx.x >> 3;
    const int tc = blockIdx.x & 7;
    const int tid = threadIdx.x;

    const float* vb = v + (size_t)bh * S * S + (size_t)tc * 32 * S;
    {
        const int c4 = (tid & 63) * 4;
        const int r  = tid >> 6;
        #pragma unroll
        for (int rr = 0; rr < 8; ++rr) {
            const int row = rr * 4 + r;
            const float4 f = *(const float4*)&vb[(size_t)row * S + c4];
            tile[row][c4 + 0] = f.x; tile[row][c4 + 1] = f.y;
            tile[row][c4 + 2] = f.z; tile[row][c4 + 3] = f.w;
        }
    }
    __syncthreads();

    const size_t obase = (size_t)bh * S * S + (size_t)tc * 8192;
    #pragma unroll
    for (int it = 0; it < 4; ++it) {
        const int id  = it * 256 + tid;      // 0..1023
        const int j   = id >> 6;
        const int l4  = (id >> 4) & 3;
        const int l15 = id & 15;
        const int d   = j * 16 + l15;
        const int t0  = l4 * 8;
        bf16x8 hv, lv, llv;
        #pragma unroll
        for (int e = 0; e < 8; ++e) {
            const float x = tile[t0 + e][d];
            const __bf16 hi = (__bf16)x;
            const float  hf = (float)hi;
            const __bf16 lo = (__bf16)(x - hf);
            const float  lf = (float)lo;
            hv[e] = hi; lv[e] = lo; llv[e] = (__bf16)(x - hf - lf);
        }
        const size_t oi = obase + (size_t)id * 8;
        *(bf16x8*)&vth[oi]  = hv;
        *(bf16x8*)&vtl[oi]  = lv;
        *(bf16x8*)&vtll[oi] = llv;
    }
}

// ===== QKT: r = (scale*Q) K^T, 3-pass split MFMA -> row-major r_hi/r_lo =====
// (verified rounds 4-8)
__global__ __launch_bounds__(NT) void qkt_kernel(
    const float* __restrict__ q, const float* __restrict__ k,
    __bf16* __restrict__ r_hi, __bf16* __restrict__ r_lo, int swz)
{
    __shared__ __align__(16) __bf16 kh[256 * 40];
    __shared__ __align__(16) __bf16 kl[256 * 40];

    const int tid = threadIdx.x;
    const int w = tid >> 6, l = tid & 63, l15 = l & 15, l4 = l >> 4;

    int L = blockIdx.x;
    if (swz) L = (blockIdx.x & 7) * ((int)gridDim.x >> 3) + (blockIdx.x >> 3);
    const int bh = L >> 2;
    const int s0 = (L & 3) << 6;

    const float* qb = q + ((size_t)bh << 16);
    const float* kb = k + ((size_t)bh << 16);

    bf16x8 qh[8], ql[8];
    {
        const float* qr = qb + (size_t)(s0 + 16 * w + l15) * S;
        #pragma unroll
        for (int kc = 0; kc < 8; ++kc) {
            const float4 f0 = *(const float4*)&qr[kc * 32 + l4 * 8];
            const float4 f1 = *(const float4*)&qr[kc * 32 + l4 * 8 + 4];
            const float xs[8] = {f0.x, f0.y, f0.z, f0.w, f1.x, f1.y, f1.z, f1.w};
            bf16x8 hv, lv;
            #pragma unroll
            for (int e = 0; e < 8; ++e) {
                const float x = xs[e] * SCALE;
                const __bf16 hi = (__bf16)x;
                hv[e] = hi; lv[e] = (__bf16)(x - (float)hi);
            }
            qh[kc] = hv; ql[kc] = lv;
        }
    }

    f32x4 acc[16];
    #pragma unroll
    for (int j = 0; j < 16; ++j) acc[j] = (f32x4){0.f, 0.f, 0.f, 0.f};

    #pragma unroll
    for (int kc = 0; kc < 8; ++kc) {
        #pragma unroll
        for (int pass = 0; pass < 8; ++pass) {
            const int row = pass * 32 + (tid >> 3);
            const int sub = tid & 7;
            const float4 f = *(const float4*)&kb[(size_t)row * S + kc * 32 + sub * 4];
            const float xs[4] = {f.x, f.y, f.z, f.w};
            bf16x4 hv, lv;
            #pragma unroll
            for (int e = 0; e < 4; ++e) {
                const __bf16 hi = (__bf16)xs[e];
                hv[e] = hi; lv[e] = (__bf16)(xs[e] - (float)hi);
            }
            *(bf16x4*)&kh[row * 40 + sub * 4] = hv;
            *(bf16x4*)&kl[row * 40 + sub * 4] = lv;
        }
        __syncthreads();
        #pragma unroll
        for (int j = 0; j < 16; ++j) {
            const int bo = (j * 16 + l15) * 40 + l4 * 8;
            const bf16x8 khf = *(const bf16x8*)&kh[bo];
            const bf16x8 klf = *(const bf16x8*)&kl[bo];
            acc[j] = MFMA(qh[kc], khf, acc[j]);
            acc[j] = MFMA(qh[kc], klf, acc[j]);
            acc[j] = MFMA(ql[kc], khf, acc[j]);
        }
        __syncthreads();
    }

    __bf16* rh_b = r_hi + ((size_t)bh << 16) + (size_t)s0 * S;
    __bf16* rl_b = r_lo + ((size_t)bh << 16) + (size_t)s0 * S;
    #pragma unroll
    for (int j = 0; j < 16; ++j) {
        #pragma unroll
        for (int rr = 0; rr < 4; ++rr) {
            const int row = 16 * w + l4 * 4 + rr;
            const int t   = j * 16 + l15;
            const float rv = acc[j][rr];
            const __bf16 hi = (__bf16)rv;
            rh_b[(size_t)row * S + t] = hi;
            rl_b[(size_t)row * S + t] = (__bf16)(rv - (float)hi);
        }
    }
}

// ===== attn2: LDS-staged V, 1-barrier-per-tc pipeline =====
#define SRC_OF(sp) ((sp) == 0 ? vth : (sp) == 1 ? vtl : vtll)

#define STAGE_LOAD(tc, NS)                                                    \
    _Pragma("unroll")                                                         \
    for (int r_ = 0; r_ < 4 * (NS); ++r_) {                                   \
        const int sp_ = r_ >> 2, qt_ = r_ & 3;                                \
        const __bf16* s_ = SRC_OF(sp_);                                       \
        stg[r_] = *(const bf16x8*)&s_[hb + (size_t)(tc) * 8192 + qt_ * 2048 + tid * 8]; \
    }

#define STAGE_WRITE(bb, NS)                                                   \
    _Pragma("unroll")                                                         \
    for (int r_ = 0; r_ < 4 * (NS); ++r_) {                                   \
        const int sp_ = r_ >> 2, qt_ = r_ & 3;                                \
        *(bf16x8*)&vbuf[bb][sp_][qt_ * 2048 + tid * 8] = stg[r_];             \
    }

__global__ __launch_bounds__(NT, 1) void attn2_kernel(
    const float* __restrict__ mask,
    const __bf16* __restrict__ r_hi, const __bf16* __restrict__ r_lo,
    const __bf16* __restrict__ vth, const __bf16* __restrict__ vtl,
    const __bf16* __restrict__ vtll,
    float* __restrict__ out, int H, int swz)
{
    __shared__ __align__(16) __bf16 vbuf[2][3][8192];   // 96 KB dbuf V-chunks
    __shared__ __align__(16) __bf16 pT[64 * 256];       // 32 KB swizzled P

    const int tid = threadIdx.x;
    const int w = tid >> 6, l = tid & 63, l15 = l & 15, l4 = l >> 4;

    int L = blockIdx.x;
    if (swz) L = (blockIdx.x & 7) * ((int)gridDim.x >> 3) + (blockIdx.x >> 3);
    const int bh = L >> 2;
    const int s0 = (L & 3) << 6;
    const int h  = bh % H;

    const size_t hb = (size_t)bh << 16;
    const float* mbase = mask + ((size_t)h << 16);

    const int arow_g = s0 + 16 * w + l15;
    const __bf16* rh_p = r_hi + hb + (size_t)arow_g * S;
    const __bf16* rl_p = r_lo + hb + (size_t)arow_g * S;
    const float*  m_p  = mbase + (size_t)arow_g * S;

    bf16x8 stg[12];

    // ---- phase 2: acc2 = (mask + r) @ V ----
    f32x4 acc2[16];
    #pragma unroll
    for (int j = 0; j < 16; ++j) acc2[j] = (f32x4){0.f, 0.f, 0.f, 0.f};

    // prologue: stage tc=0, load r/mask for tc=0
    STAGE_LOAD(0, 3);
    STAGE_WRITE(0, 3);
    bf16x8 rhc, rlc; float4 m0c, m1c;
    {
        const int ko_ = l4 * 8;
        rhc = *(const bf16x8*)&rh_p[ko_];
        rlc = *(const bf16x8*)&rl_p[ko_];
        m0c = *(const float4*)&m_p[ko_];
        m1c = *(const float4*)&m_p[ko_ + 4];
    }
    __syncthreads();

    #pragma unroll
    for (int tc = 0; tc < 8; ++tc) {
        bf16x8 rhn, rln; float4 m0n, m1n;
        if (tc < 7) {
            STAGE_LOAD(tc + 1, 3);               // global->reg, in flight
            const int ko_ = (tc + 1) * 32 + l4 * 8;
            rhn = *(const bf16x8*)&rh_p[ko_];
            rln = *(const bf16x8*)&rl_p[ko_];
            m0n = *(const float4*)&m_p[ko_];
            m1n = *(const float4*)&m_p[ko_ + 4];
        }
        bf16x8 mf;
        mf[0] = (__bf16)m0c.x; mf[1] = (__bf16)m0c.y;
        mf[2] = (__bf16)m0c.z; mf[3] = (__bf16)m0c.w;
        mf[4] = (__bf16)m1c.x; mf[5] = (__bf16)m1c.y;
        mf[6] = (__bf16)m1c.z; mf[7] = (__bf16)m1c.w;

        const int cur = tc & 1;
        #pragma unroll
        for (int j = 0; j < 16; ++j) {
            const int fo = j * 512 + l * 8;      // lane-linear, conflict-free
            const bf16x8 vh  = *(const bf16x8*)&vbuf[cur][0][fo];
            const bf16x8 vl  = *(const bf16x8*)&vbuf[cur][1][fo];
            const bf16x8 vll = *(const bf16x8*)&vbuf[cur][2][fo];
            acc2[j] = MFMA(mf,  vh,  acc2[j]);
            acc2[j] = MFMA(mf,  vl,  acc2[j]);
            acc2[j] = MFMA(mf,  vll, acc2[j]);
            acc2[j] = MFMA(rhc, vh,  acc2[j]);
            acc2[j] = MFMA(rhc, vl,  acc2[j]);
            acc2[j] = MFMA(rlc, vh,  acc2[j]);
        }
        if (tc < 7) STAGE_WRITE((tc + 1) & 1, 3);  // vmcnt drained here (overlapped)
        __syncthreads();
        if (tc < 7) { rhc = rhn; rlc = rln; m0c = m0n; m1c = m1n; }
    }

    // stage phase-3 tc=0 (vh, vl only) — lands during softmax
    STAGE_LOAD(0, 2);

    // ---- masked fill + row softmax (in-register, per 16-lane group) ----
    #pragma unroll
    for (int rr = 0; rr < 4; ++rr) {
        const int srow = 16 * w + l4 * 4 + rr;
        const float* mrow = mbase + (size_t)(s0 + srow) * S;
        float mx = -3.4e38f;
        #pragma unroll
        for (int j = 0; j < 16; ++j) {
            const float mval = mrow[j * 16 + l15];
            const float a = (mval == 0.0f) ? -1e9f : acc2[j][rr];
            acc2[j][rr] = a;
            mx = fmaxf(mx, a);
        }
        #pragma unroll
        for (int off = 1; off < 16; off <<= 1)
            mx = fmaxf(mx, __shfl_xor(mx, off, 64));
        float sm = 0.f;
        #pragma unroll
        for (int j = 0; j < 16; ++j) {
            const float e = __expf(acc2[j][rr] - mx);
            acc2[j][rr] = e;
            sm += e;
        }
        #pragma unroll
        for (int off = 1; off < 16; off <<= 1)
            sm += __shfl_xor(sm, off, 64);
        const float inv = 1.0f / sm;
        #pragma unroll
        for (int j = 0; j < 16; ++j) {
            const int t = j * 16 + l15;
            pT[((srow << 8) + t) ^ ((srow & 7) << 3)] = (__bf16)(acc2[j][rr] * inv);
        }
    }
    STAGE_WRITE(0, 2);      // vbuf[0] free (last read at tc=6, two barriers ago)
    __syncthreads();        // pT + vbuf[0] visible

    // ---- phase 3: out = P @ V ----
    f32x4 acc3[16];
    #pragma unroll
    for (int j = 0; j < 16; ++j) acc3[j] = (f32x4){0.f, 0.f, 0.f, 0.f};

    const int prow = 16 * w + l15;
    #pragma unroll
    for (int tc = 0; tc < 8; ++tc) {
        if (tc < 7) STAGE_LOAD(tc + 1, 2);
        const int pb = ((prow << 8) + tc * 32 + l4 * 8) ^ ((prow & 7) << 3);
        const bf16x8 pa = *(const bf16x8*)&pT[pb];
        const int cur = tc & 1;
        #pragma unroll
        for (int j = 0; j < 16; ++j) {
            const int fo = j * 512 + l * 8;
            acc3[j] = MFMA(pa, *(const bf16x8*)&vbuf[cur][0][fo], acc3[j]);
            acc3[j] = MFMA(pa, *(const bf16x8*)&vbuf[cur][1][fo], acc3[j]);
        }
        if (tc < 7) STAGE_WRITE((tc + 1) & 1, 2);
        __syncthreads();
    }

    float* ob = out + hb + (size_t)s0 * S;
    #pragma unroll
    for (int j = 0; j < 16; ++j) {
        #pragma unroll
        for (int rr = 0; rr < 4; ++rr)
            ob[(size_t)(16 * w + l4 * 4 + rr) * S + j * 16 + l15] = acc3[j][rr];
    }
}

// ================= fallback: fp32 path (verified round 2) =================
__global__ __launch_bounds__(NT) void transpose_k_kernel(
    const float* __restrict__ k, float* __restrict__ kt)
{
    __shared__ float tile[64][65];
    const int tileIdx = blockIdx.x & 15;
    const int bh      = blockIdx.x >> 4;
    const int ti = (tileIdx >> 2) * 64;
    const int tj = (tileIdx & 3) * 64;
    const float* kb = k  + (size_t)bh * S * S;
    float*      ktb = kt + (size_t)bh * S * S;
    const int c  = threadIdx.x & 63;
    const int r4 = threadIdx.x >> 6;
    #pragma unroll
    for (int rr = 0; rr < 64; rr += 4)
        tile[rr + r4][c] = kb[(size_t)(ti + rr + r4) * S + tj + c];
    __syncthreads();
    #pragma unroll
    for (int rr = 0; rr < 64; rr += 4)
        ktb[(size_t)(tj + rr + r4) * S + ti + c] = tile[c][rr + r4];
}

template <int RPB>
__global__ __launch_bounds__(NT) void fused_attn_rpb(
    const float* __restrict__ q, const float* __restrict__ kt,
    const float* __restrict__ v, const float* __restrict__ mask,
    float* __restrict__ out, int nbh, int H, int swizzle)
{
    __shared__ float qT[S][RPB];
    __shared__ float sT[S][RPB];
    __shared__ float redbuf[4][RPB];

    const int tid = threadIdx.x;
    constexpr int NRB = S / RPB;
    int bh, rb;
    if (swizzle) {
        const int xcd  = blockIdx.x & 7;
        const int slot = blockIdx.x >> 3;
        const int hpx  = nbh >> 3;
        bh = xcd * hpx + (slot % hpx);
        rb = slot / hpx;
    } else {
        bh = blockIdx.x / NRB;
        rb = blockIdx.x % NRB;
    }
    const int h  = bh % H;
    const int s0 = rb * RPB;

    const float* qb  = q    + (size_t)bh * S * S;
    const float* ktb = kt   + (size_t)bh * S * S;
    const float* vb  = v    + (size_t)bh * S * S;
    const float* mb  = mask + (size_t)h  * S * S + (size_t)s0 * S;
    float*       ob  = out  + (size_t)bh * S * S + (size_t)s0 * S;

    #pragma unroll
    for (int si = 0; si < RPB; ++si)
        qT[tid][si] = qb[(size_t)(s0 + si) * S + tid];
    __syncthreads();

    {
        float acc[RPB];
        #pragma unroll
        for (int si = 0; si < RPB; ++si) acc[si] = 0.f;
        #pragma unroll 4
        for (int i = 0; i < S; ++i) {
            const float kv = ktb[(size_t)i * S + tid];
            #pragma unroll
            for (int si4 = 0; si4 < RPB; si4 += 4) {
                const float4 qa = *reinterpret_cast<const float4*>(&qT[i][si4]);
                acc[si4+0] = fmaf(qa.x, kv, acc[si4+0]);
                acc[si4+1] = fmaf(qa.y, kv, acc[si4+1]);
                acc[si4+2] = fmaf(qa.z, kv, acc[si4+2]);
                acc[si4+3] = fmaf(qa.w, kv, acc[si4+3]);
            }
        }
        #pragma unroll
        for (int si4 = 0; si4 < RPB; si4 += 4) {
            float4 t4;
            t4.x = fmaf(acc[si4+0], SCALE, mb[(size_t)(si4+0)*S + tid]);
            t4.y = fmaf(acc[si4+1], SCALE, mb[(size_t)(si4+1)*S + tid]);
            t4.z = fmaf(acc[si4+2], SCALE, mb[(size_t)(si4+2)*S + tid]);
            t4.w = fmaf(acc[si4+3], SCALE, mb[(size_t)(si4+3)*S + tid]);
            *reinterpret_cast<float4*>(&sT[tid][si4]) = t4;
        }
    }
    __syncthreads();

    float a1[RPB];
    #pragma unroll
    for (int si = 0; si < RPB; ++si) a1[si] = 0.f;
    #pragma unroll 2
    for (int t = 0; t < S; ++t) {
        const float vv = vb[(size_t)t * S + tid];
        #pragma unroll
        for (int si4 = 0; si4 < RPB; si4 += 4) {
            const float4 pa = *reinterpret_cast<const float4*>(&sT[t][si4]);
            a1[si4+0] = fmaf(pa.x, vv, a1[si4+0]);
            a1[si4+1] = fmaf(pa.y, vv, a1[si4+1]);
            a1[si4+2] = fmaf(pa.z, vv, a1[si4+2]);
            a1[si4+3] = fmaf(pa.w, vv, a1[si4+3]);
        }
    }
    #pragma unroll
    for (int si = 0; si < RPB; ++si)
        if (mb[(size_t)si * S + tid] == 0.0f) a1[si] = -1e9f;

    const int lane = tid & 63;
    const int wv   = tid >> 6;
    #pragma unroll
    for (int si = 0; si < RPB; ++si) {
        float m = a1[si];
        #pragma unroll
        for (int off = 32; off > 0; off >>= 1)
            m = fmaxf(m, __shfl_down(m, off, 64));
        if (lane == 0) redbuf[wv][si] = m;
    }
    __syncthreads();
    float e[RPB];
    #pragma unroll
    for (int si = 0; si < RPB; ++si) {
        const float m = fmaxf(fmaxf(redbuf[0][si], redbuf[1][si]),
                              fmaxf(redbuf[2][si], redbuf[3][si]));
        e[si] = __expf(a1[si] - m);
    }
    __syncthreads();
    #pragma unroll
    for (int si = 0; si < RPB; ++si) {
        float sm = e[si];
        #pragma unroll
        for (int off = 32; off > 0; off >>= 1)
            sm += __shfl_down(sm, off, 64);
        if (lane == 0) redbuf[wv][si] = sm;
    }
    __syncthreads();
    #pragma unroll
    for (int si4 = 0; si4 < RPB; si4 += 4) {
        float4 t4;
        #pragma unroll
        for (int jj = 0; jj < 4; ++jj) {
            const int si = si4 + jj;
            const float sm = redbuf[0][si] + redbuf[1][si] +
                             redbuf[2][si] + redbuf[3][si];
            (&t4.x)[jj] = e[si] / sm;
        }
        *reinterpret_cast<float4*>(&sT[tid][si4]) = t4;
    }
    __syncthreads();

    float o[RPB];
    #pragma unroll
    for (int si = 0; si < RPB; ++si) o[si] = 0.f;
    #pragma unroll 2
    for (int t = 0; t < S; ++t) {
        const float vv = vb[(size_t)t * S + tid];
        #pragma unroll
        for (int si4 = 0; si4 < RPB; si4 += 4) {
            const float4 pa = *reinterpret_cast<const float4*>(&sT[t][si4]);
            o[si4+0] = fmaf(pa.x, vv, o[si4+0]);
            o[si4+1] = fmaf(pa.y, vv, o[si4+1]);
            o[si4+2] = fmaf(pa.z, vv, o[si4+2]);
            o[si4+3] = fmaf(pa.w, vv, o[si4+3]);
        }
    }
    #pragma unroll
    for (int si = 0; si < RPB; ++si)
        ob[(size_t)si * S + tid] = o[si];
}

extern "C" void kernel_launch(void* const* d_in, const int* in_sizes, int n_in,
                              void* d_out, int out_size, void* d_ws, size_t ws_size,
                              hipStream_t stream) {
    const float* q    = (const float*)d_in[0];
    const float* k    = (const float*)d_in[1];
    const float* v    = (const float*)d_in[2];
    const float* mask = (const float*)d_in[3];
    float* out = (float*)d_out;

    const int nbh = in_sizes[0] / (S * S);   // B*H
    const int H   = in_sizes[3] / (S * S);   // heads
    const size_t he = (size_t)nbh * S * S;
    const size_t need = he * sizeof(__bf16) * 5;   // vth,vtl,vtll,r_hi,r_lo
    const size_t kt_bytes = he * sizeof(float);

    if (ws_size >= need) {
        __bf16* vth  = (__bf16*)d_ws;
        __bf16* vtl  = vth + he;
        __bf16* vtll = vtl + he;
        __bf16* rhi  = vtll + he;
        __bf16* rlo  = rhi + he;
        const int nblk = nbh * 4;
        const int swz = (nblk % 8 == 0) ? 1 : 0;
        vsplit_kernel<<<dim3(nbh * 8), NT, 0, stream>>>(v, vth, vtl, vtll);
        qkt_kernel<<<dim3(nblk), NT, 0, stream>>>(q, k, rhi, rlo, swz);
        attn2_kernel<<<dim3(nblk), NT, 0, stream>>>(
            mask, rhi, rlo, vth, vtl, vtll, out, H, swz);
    } else if (ws_size >= kt_bytes) {
        float* kt = (float*)d_ws;
        transpose_k_kernel<<<dim3(nbh * 16), NT, 0, stream>>>(k, kt);
        constexpr int RPB = 16;
        const int grid = nbh * (S / RPB);
        const int swz = (nbh % 8 == 0) ? 1 : 0;
        fused_attn_rpb<RPB><<<dim3(grid), NT, 0, stream>>>(
            q, kt, v, mask, out, nbh, H, swz);
    }
}

// Round 11
// 100.067 us; speedup vs baseline: 3.1071x; 1.1547x over previous
//
#include <hip/hip_runtime.h>
#include <math.h>

namespace {
constexpr int S  = 256;
constexpr int NT = 256;
constexpr float SCALE = 0.0625f;  // 1/sqrt(256)
}

typedef __bf16 bf16x4 __attribute__((ext_vector_type(4)));
typedef __bf16 bf16x8 __attribute__((ext_vector_type(8)));
typedef float  f32x4  __attribute__((ext_vector_type(4)));

#define MFMA(a, b, c) __builtin_amdgcn_mfma_f32_16x16x32_bf16((a), (b), (c), 0, 0, 0)

// ===== prep: V^T 3-way bf16 split, FRAGMENT-PACKED (verified round 9/10) =====
// packed idx (per bh): tc*8192 + j*512 + lane*8 + e
//   where d = j*16 + (lane&15), t = tc*32 + (lane>>4)*8 + e
__global__ __launch_bounds__(NT) void vsplit_kernel(
    const float* __restrict__ v,
    __bf16* __restrict__ vth, __bf16* __restrict__ vtl, __bf16* __restrict__ vtll)
{
    __shared__ float tile[32][257];     // [t_local][d]
    const int bh = blockIdx.x >> 3;
    const int tc = blockIdx.x & 7;
    const int tid = threadIdx.x;

    const float* vb = v + (size_t)bh * S * S + (size_t)tc * 32 * S;
    {
        const int c4 = (tid & 63) * 4;
        const int r  = tid >> 6;
        #pragma unroll
        for (int rr = 0; rr < 8; ++rr) {
            const int row = rr * 4 + r;
            const float4 f = *(const float4*)&vb[(size_t)row * S + c4];
            tile[row][c4 + 0] = f.x; tile[row][c4 + 1] = f.y;
            tile[row][c4 + 2] = f.z; tile[row][c4 + 3] = f.w;
        }
    }
    __syncthreads();

    const size_t obase = (size_t)bh * S * S + (size_t)tc * 8192;
    #pragma unroll
    for (int it = 0; it < 4; ++it) {
        const int id  = it * 256 + tid;      // 0..1023
        const int j   = id >> 6;
        const int l4  = (id >> 4) & 3;
        const int l15 = id & 15;
        const int d   = j * 16 + l15;
        const int t0  = l4 * 8;
        bf16x8 hv, lv, llv;
        #pragma unroll
        for (int e = 0; e < 8; ++e) {
            const float x = tile[t0 + e][d];
            const __bf16 hi = (__bf16)x;
            const float  hf = (float)hi;
            const __bf16 lo = (__bf16)(x - hf);
            const float  lf = (float)lo;
            hv[e] = hi; lv[e] = lo; llv[e] = (__bf16)(x - hf - lf);
        }
        const size_t oi = obase + (size_t)id * 8;
        *(bf16x8*)&vth[oi]  = hv;
        *(bf16x8*)&vtl[oi]  = lv;
        *(bf16x8*)&vtll[oi] = llv;
    }
}

// ===== QKT: r = (scale*Q) K^T, 3-pass split MFMA -> row-major r_hi/r_lo =====
// (verified rounds 4-10)
__global__ __launch_bounds__(NT) void qkt_kernel(
    const float* __restrict__ q, const float* __restrict__ k,
    __bf16* __restrict__ r_hi, __bf16* __restrict__ r_lo, int swz)
{
    __shared__ __align__(16) __bf16 kh[256 * 40];
    __shared__ __align__(16) __bf16 kl[256 * 40];

    const int tid = threadIdx.x;
    const int w = tid >> 6, l = tid & 63, l15 = l & 15, l4 = l >> 4;

    int L = blockIdx.x;
    if (swz) L = (blockIdx.x & 7) * ((int)gridDim.x >> 3) + (blockIdx.x >> 3);
    const int bh = L >> 2;
    const int s0 = (L & 3) << 6;

    const float* qb = q + ((size_t)bh << 16);
    const float* kb = k + ((size_t)bh << 16);

    bf16x8 qh[8], ql[8];
    {
        const float* qr = qb + (size_t)(s0 + 16 * w + l15) * S;
        #pragma unroll
        for (int kc = 0; kc < 8; ++kc) {
            const float4 f0 = *(const float4*)&qr[kc * 32 + l4 * 8];
            const float4 f1 = *(const float4*)&qr[kc * 32 + l4 * 8 + 4];
            const float xs[8] = {f0.x, f0.y, f0.z, f0.w, f1.x, f1.y, f1.z, f1.w};
            bf16x8 hv, lv;
            #pragma unroll
            for (int e = 0; e < 8; ++e) {
                const float x = xs[e] * SCALE;
                const __bf16 hi = (__bf16)x;
                hv[e] = hi; lv[e] = (__bf16)(x - (float)hi);
            }
            qh[kc] = hv; ql[kc] = lv;
        }
    }

    f32x4 acc[16];
    #pragma unroll
    for (int j = 0; j < 16; ++j) acc[j] = (f32x4){0.f, 0.f, 0.f, 0.f};

    #pragma unroll
    for (int kc = 0; kc < 8; ++kc) {
        #pragma unroll
        for (int pass = 0; pass < 8; ++pass) {
            const int row = pass * 32 + (tid >> 3);
            const int sub = tid & 7;
            const float4 f = *(const float4*)&kb[(size_t)row * S + kc * 32 + sub * 4];
            const float xs[4] = {f.x, f.y, f.z, f.w};
            bf16x4 hv, lv;
            #pragma unroll
            for (int e = 0; e < 4; ++e) {
                const __bf16 hi = (__bf16)xs[e];
                hv[e] = hi; lv[e] = (__bf16)(xs[e] - (float)hi);
            }
            *(bf16x4*)&kh[row * 40 + sub * 4] = hv;
            *(bf16x4*)&kl[row * 40 + sub * 4] = lv;
        }
        __syncthreads();
        #pragma unroll
        for (int j = 0; j < 16; ++j) {
            const int bo = (j * 16 + l15) * 40 + l4 * 8;
            const bf16x8 khf = *(const bf16x8*)&kh[bo];
            const bf16x8 klf = *(const bf16x8*)&kl[bo];
            acc[j] = MFMA(qh[kc], khf, acc[j]);
            acc[j] = MFMA(qh[kc], klf, acc[j]);
            acc[j] = MFMA(ql[kc], khf, acc[j]);
        }
        __syncthreads();
    }

    __bf16* rh_b = r_hi + ((size_t)bh << 16) + (size_t)s0 * S;
    __bf16* rl_b = r_lo + ((size_t)bh << 16) + (size_t)s0 * S;
    #pragma unroll
    for (int j = 0; j < 16; ++j) {
        #pragma unroll
        for (int rr = 0; rr < 4; ++rr) {
            const int row = 16 * w + l4 * 4 + rr;
            const int t   = j * 16 + l15;
            const float rv = acc[j][rr];
            const __bf16 hi = (__bf16)rv;
            rh_b[(size_t)row * S + t] = hi;
            rl_b[(size_t)row * S + t] = (__bf16)(rv - (float)hi);
        }
    }
}

// ===== attn2: 64 KB aliased-arena LDS pipeline, 2 blocks/CU =====
// arena layout:
//   phase 2: V chunk [3][8192] at [0, 24576)      (48 KB, single-buffered)
//   phase 3: pT      [16384]   at [0, 16384)      (32 KB)
//            V chunk [2][8192] at [16384, 32768)  (32 KB, single-buffered)
#define SRC_OF(sp) ((sp) == 0 ? vth : (sp) == 1 ? vtl : vtll)

#define P2_LOAD(tc)                                                           \
    _Pragma("unroll")                                                         \
    for (int r_ = 0; r_ < 12; ++r_) {                                         \
        const int sp_ = r_ >> 2, qt_ = r_ & 3;                                \
        const __bf16* s_ = SRC_OF(sp_);                                       \
        stg[r_] = *(const bf16x8*)&s_[hb + (size_t)(tc) * 8192 + qt_ * 2048 + tid * 8]; \
    }

#define P2_WRITE()                                                            \
    _Pragma("unroll")                                                         \
    for (int r_ = 0; r_ < 12; ++r_) {                                         \
        const int sp_ = r_ >> 2, qt_ = r_ & 3;                                \
        *(bf16x8*)&arena[sp_ * 8192 + qt_ * 2048 + tid * 8] = stg[r_];        \
    }

#define P3_LOAD(tc)                                                           \
    _Pragma("unroll")                                                         \
    for (int r_ = 0; r_ < 8; ++r_) {                                          \
        const int sp_ = r_ >> 2, qt_ = r_ & 3;                                \
        const __bf16* s_ = SRC_OF(sp_);                                       \
        stg[r_] = *(const bf16x8*)&s_[hb + (size_t)(tc) * 8192 + qt_ * 2048 + tid * 8]; \
    }

#define P3_WRITE()                                                            \
    _Pragma("unroll")                                                         \
    for (int r_ = 0; r_ < 8; ++r_) {                                          \
        const int sp_ = r_ >> 2, qt_ = r_ & 3;                                \
        *(bf16x8*)&arena[16384 + sp_ * 8192 + qt_ * 2048 + tid * 8] = stg[r_];\
    }

__global__ __launch_bounds__(NT, 2) void attn2_kernel(
    const float* __restrict__ mask,
    const __bf16* __restrict__ r_hi, const __bf16* __restrict__ r_lo,
    const __bf16* __restrict__ vth, const __bf16* __restrict__ vtl,
    const __bf16* __restrict__ vtll,
    float* __restrict__ out, int H, int swz)
{
    __shared__ __align__(16) __bf16 arena[32768];   // 64 KB

    const int tid = threadIdx.x;
    const int w = tid >> 6, l = tid & 63, l15 = l & 15, l4 = l >> 4;

    int L = blockIdx.x;
    if (swz) L = (blockIdx.x & 7) * ((int)gridDim.x >> 3) + (blockIdx.x >> 3);
    const int bh = L >> 2;
    const int s0 = (L & 3) << 6;
    const int h  = bh % H;

    const size_t hb = (size_t)bh << 16;
    const float* mbase = mask + ((size_t)h << 16);

    const int arow_g = s0 + 16 * w + l15;
    const __bf16* rh_p = r_hi + hb + (size_t)arow_g * S;
    const __bf16* rl_p = r_lo + hb + (size_t)arow_g * S;
    const float*  m_p  = mbase + (size_t)arow_g * S;

    bf16x8 stg[12];

    // ---- phase 2: acc2 = (mask + r) @ V ----
    f32x4 acc2[16];
    #pragma unroll
    for (int j = 0; j < 16; ++j) acc2[j] = (f32x4){0.f, 0.f, 0.f, 0.f};

    // prologue: stage tc=0, preload tc=1 into regs, r/mask tc=0
    P2_LOAD(0);
    P2_WRITE();
    P2_LOAD(1);
    bf16x8 rhc, rlc; float4 m0c, m1c;
    {
        const int ko_ = l4 * 8;
        rhc = *(const bf16x8*)&rh_p[ko_];
        rlc = *(const bf16x8*)&rl_p[ko_];
        m0c = *(const float4*)&m_p[ko_];
        m1c = *(const float4*)&m_p[ko_ + 4];
    }
    __syncthreads();

    #pragma unroll
    for (int tc = 0; tc < 8; ++tc) {
        bf16x8 rhn, rln; float4 m0n, m1n;
        if (tc < 7) {
            const int ko_ = (tc + 1) * 32 + l4 * 8;
            rhn = *(const bf16x8*)&rh_p[ko_];
            rln = *(const bf16x8*)&rl_p[ko_];
            m0n = *(const float4*)&m_p[ko_];
            m1n = *(const float4*)&m_p[ko_ + 4];
        }
        bf16x8 mf;
        mf[0] = (__bf16)m0c.x; mf[1] = (__bf16)m0c.y;
        mf[2] = (__bf16)m0c.z; mf[3] = (__bf16)m0c.w;
        mf[4] = (__bf16)m1c.x; mf[5] = (__bf16)m1c.y;
        mf[6] = (__bf16)m1c.z; mf[7] = (__bf16)m1c.w;

        #pragma unroll
        for (int j = 0; j < 16; ++j) {
            const int fo = j * 512 + l * 8;      // lane-linear, conflict-free
            const bf16x8 vh  = *(const bf16x8*)&arena[fo];
            const bf16x8 vl  = *(const bf16x8*)&arena[8192 + fo];
            const bf16x8 vll = *(const bf16x8*)&arena[16384 + fo];
            acc2[j] = MFMA(mf,  vh,  acc2[j]);
            acc2[j] = MFMA(mf,  vl,  acc2[j]);
            acc2[j] = MFMA(mf,  vll, acc2[j]);
            acc2[j] = MFMA(rhc, vh,  acc2[j]);
            acc2[j] = MFMA(rhc, vl,  acc2[j]);
            acc2[j] = MFMA(rlc, vh,  acc2[j]);
        }
        __syncthreads();                 // all reads of arena done
        if (tc < 7) {
            P2_WRITE();                  // stg holds tc+1 (vmcnt drained here)
            if (tc < 6) P2_LOAD(tc + 2); // next loads in flight across MFMA
            rhc = rhn; rlc = rln; m0c = m0n; m1c = m1n;
            __syncthreads();             // writes visible
        }
    }

    // stage phase-3 tc=0 (vh, vl) — loads land during softmax
    P3_LOAD(0);

    // ---- masked fill + row softmax (in-register, per 16-lane group) ----
    #pragma unroll
    for (int rr = 0; rr < 4; ++rr) {
        const int srow = 16 * w + l4 * 4 + rr;
        const float* mrow = mbase + (size_t)(s0 + srow) * S;
        float mx = -3.4e38f;
        #pragma unroll
        for (int j = 0; j < 16; ++j) {
            const float mval = mrow[j * 16 + l15];
            const float a = (mval == 0.0f) ? -1e9f : acc2[j][rr];
            acc2[j][rr] = a;
            mx = fmaxf(mx, a);
        }
        #pragma unroll
        for (int off = 1; off < 16; off <<= 1)
            mx = fmaxf(mx, __shfl_xor(mx, off, 64));
        float sm = 0.f;
        #pragma unroll
        for (int j = 0; j < 16; ++j) {
            const float e = __expf(acc2[j][rr] - mx);
            acc2[j][rr] = e;
            sm += e;
        }
        #pragma unroll
        for (int off = 1; off < 16; off <<= 1)
            sm += __shfl_xor(sm, off, 64);
        const float inv = 1.0f / sm;
        #pragma unroll
        for (int j = 0; j < 16; ++j) {
            const int t = j * 16 + l15;
            arena[((srow << 8) + t) ^ ((srow & 7) << 3)] = (__bf16)(acc2[j][rr] * inv);
        }
    }
    P3_WRITE();             // [16K,32K) region free (reads done at tc=7 barrier)
    P3_LOAD(1);
    __syncthreads();        // pT + chunk 0 visible

    // ---- phase 3: out = P @ V ----
    f32x4 acc3[16];
    #pragma unroll
    for (int j = 0; j < 16; ++j) acc3[j] = (f32x4){0.f, 0.f, 0.f, 0.f};

    const int prow = 16 * w + l15;
    #pragma unroll
    for (int tc = 0; tc < 8; ++tc) {
        const int pb = ((prow << 8) + tc * 32 + l4 * 8) ^ ((prow & 7) << 3);
        const bf16x8 pa = *(const bf16x8*)&arena[pb];
        #pragma unroll
        for (int j = 0; j < 16; ++j) {
            const int fo = 16384 + j * 512 + l * 8;
            acc3[j] = MFMA(pa, *(const bf16x8*)&arena[fo], acc3[j]);
            acc3[j] = MFMA(pa, *(const bf16x8*)&arena[8192 + fo], acc3[j]);
        }
        __syncthreads();
        if (tc < 7) {
            P3_WRITE();
            if (tc < 6) P3_LOAD(tc + 2);
            __syncthreads();
        }
    }

    float* ob = out + hb + (size_t)s0 * S;
    #pragma unroll
    for (int j = 0; j < 16; ++j) {
        #pragma unroll
        for (int rr = 0; rr < 4; ++rr)
            ob[(size_t)(16 * w + l4 * 4 + rr) * S + j * 16 + l15] = acc3[j][rr];
    }
}

// ================= fallback: fp32 path (verified round 2) =================
__global__ __launch_bounds__(NT) void transpose_k_kernel(
    const float* __restrict__ k, float* __restrict__ kt)
{
    __shared__ float tile[64][65];
    const int tileIdx = blockIdx.x & 15;
    const int bh      = blockIdx.x >> 4;
    const int ti = (tileIdx >> 2) * 64;
    const int tj = (tileIdx & 3) * 64;
    const float* kb = k  + (size_t)bh * S * S;
    float*      ktb = kt + (size_t)bh * S * S;
    const int c  = threadIdx.x & 63;
    const int r4 = threadIdx.x >> 6;
    #pragma unroll
    for (int rr = 0; rr < 64; rr += 4)
        tile[rr + r4][c] = kb[(size_t)(ti + rr + r4) * S + tj + c];
    __syncthreads();
    #pragma unroll
    for (int rr = 0; rr < 64; rr += 4)
        ktb[(size_t)(tj + rr + r4) * S + ti + c] = tile[c][rr + r4];
}

template <int RPB>
__global__ __launch_bounds__(NT) void fused_attn_rpb(
    const float* __restrict__ q, const float* __restrict__ kt,
    const float* __restrict__ v, const float* __restrict__ mask,
    float* __restrict__ out, int nbh, int H, int swizzle)
{
    __shared__ float qT[S][RPB];
    __shared__ float sT[S][RPB];
    __shared__ float redbuf[4][RPB];

    const int tid = threadIdx.x;
    constexpr int NRB = S / RPB;
    int bh, rb;
    if (swizzle) {
        const int xcd  = blockIdx.x & 7;
        const int slot = blockIdx.x >> 3;
        const int hpx  = nbh >> 3;
        bh = xcd * hpx + (slot % hpx);
        rb = slot / hpx;
    } else {
        bh = blockIdx.x / NRB;
        rb = blockIdx.x % NRB;
    }
    const int h  = bh % H;
    const int s0 = rb * RPB;

    const float* qb  = q    + (size_t)bh * S * S;
    const float* ktb = kt   + (size_t)bh * S * S;
    const float* vb  = v    + (size_t)bh * S * S;
    const float* mb  = mask + (size_t)h  * S * S + (size_t)s0 * S;
    float*       ob  = out  + (size_t)bh * S * S + (size_t)s0 * S;

    #pragma unroll
    for (int si = 0; si < RPB; ++si)
        qT[tid][si] = qb[(size_t)(s0 + si) * S + tid];
    __syncthreads();

    {
        float acc[RPB];
        #pragma unroll
        for (int si = 0; si < RPB; ++si) acc[si] = 0.f;
        #pragma unroll 4
        for (int i = 0; i < S; ++i) {
            const float kv = ktb[(size_t)i * S + tid];
            #pragma unroll
            for (int si4 = 0; si4 < RPB; si4 += 4) {
                const float4 qa = *reinterpret_cast<const float4*>(&qT[i][si4]);
                acc[si4+0] = fmaf(qa.x, kv, acc[si4+0]);
                acc[si4+1] = fmaf(qa.y, kv, acc[si4+1]);
                acc[si4+2] = fmaf(qa.z, kv, acc[si4+2]);
                acc[si4+3] = fmaf(qa.w, kv, acc[si4+3]);
            }
        }
        #pragma unroll
        for (int si4 = 0; si4 < RPB; si4 += 4) {
            float4 t4;
            t4.x = fmaf(acc[si4+0], SCALE, mb[(size_t)(si4+0)*S + tid]);
            t4.y = fmaf(acc[si4+1], SCALE, mb[(size_t)(si4+1)*S + tid]);
            t4.z = fmaf(acc[si4+2], SCALE, mb[(size_t)(si4+2)*S + tid]);
            t4.w = fmaf(acc[si4+3], SCALE, mb[(size_t)(si4+3)*S + tid]);
            *reinterpret_cast<float4*>(&sT[tid][si4]) = t4;
        }
    }
    __syncthreads();

    float a1[RPB];
    #pragma unroll
    for (int si = 0; si < RPB; ++si) a1[si] = 0.f;
    #pragma unroll 2
    for (int t = 0; t < S; ++t) {
        const float vv = vb[(size_t)t * S + tid];
        #pragma unroll
        for (int si4 = 0; si4 < RPB; si4 += 4) {
            const float4 pa = *reinterpret_cast<const float4*>(&sT[t][si4]);
            a1[si4+0] = fmaf(pa.x, vv, a1[si4+0]);
            a1[si4+1] = fmaf(pa.y, vv, a1[si4+1]);
            a1[si4+2] = fmaf(pa.z, vv, a1[si4+2]);
            a1[si4+3] = fmaf(pa.w, vv, a1[si4+3]);
        }
    }
    #pragma unroll
    for (int si = 0; si < RPB; ++si)
        if (mb[(size_t)si * S + tid] == 0.0f) a1[si] = -1e9f;

    const int lane = tid & 63;
    const int wv   = tid >> 6;
    #pragma unroll
    for (int si = 0; si < RPB; ++si) {
        float m = a1[si];
        #pragma unroll
        for (int off = 32; off > 0; off >>= 1)
            m = fmaxf(m, __shfl_down(m, off, 64));
        if (lane == 0) redbuf[wv][si] = m;
    }
    __syncthreads();
    float e[RPB];
    #pragma unroll
    for (int si = 0; si < RPB; ++si) {
        const float m = fmaxf(fmaxf(redbuf[0][si], redbuf[1][si]),
                              fmaxf(redbuf[2][si], redbuf[3][si]));
        e[si] = __expf(a1[si] - m);
    }
    __syncthreads();
    #pragma unroll
    for (int si = 0; si < RPB; ++si) {
        float sm = e[si];
        #pragma unroll
        for (int off = 32; off > 0; off >>= 1)
            sm += __shfl_down(sm, off, 64);
        if (lane == 0) redbuf[wv][si] = sm;
    }
    __syncthreads();
    #pragma unroll
    for (int si4 = 0; si4 < RPB; si4 += 4) {
        float4 t4;
        #pragma unroll
        for (int jj = 0; jj < 4; ++jj) {
            const int si = si4 + jj;
            const float sm = redbuf[0][si] + redbuf[1][si] +
                             redbuf[2][si] + redbuf[3][si];
            (&t4.x)[jj] = e[si] / sm;
        }
        *reinterpret_cast<float4*>(&sT[tid][si4]) = t4;
    }
    __syncthreads();

    float o[RPB];
    #pragma unroll
    for (int si = 0; si < RPB; ++si) o[si] = 0.f;
    #pragma unroll 2
    for (int t = 0; t < S; ++t) {
        const float vv = vb[(size_t)t * S + tid];
        #pragma unroll
        for (int si4 = 0; si4 < RPB; si4 += 4) {
            const float4 pa = *reinterpret_cast<const float4*>(&sT[t][si4]);
            o[si4+0] = fmaf(pa.x, vv, o[si4+0]);
            o[si4+1] = fmaf(pa.y, vv, o[si4+1]);
            o[si4+2] = fmaf(pa.z, vv, o[si4+2]);
            o[si4+3] = fmaf(pa.w, vv, o[si4+3]);
        }
    }
    #pragma unroll
    for (int si = 0; si < RPB; ++si)
        ob[(size_t)si * S + tid] = o[si];
}

extern "C" void kernel_launch(void* const* d_in, const int* in_sizes, int n_in,
                              void* d_out, int out_size, void* d_ws, size_t ws_size,
                              hipStream_t stream) {
    const float* q    = (const float*)d_in[0];
    const float* k    = (const float*)d_in[1];
    const float* v    = (const float*)d_in[2];
    const float* mask = (const float*)d_in[3];
    float* out = (float*)d_out;

    const int nbh = in_sizes[0] / (S * S);   // B*H
    const int H   = in_sizes[3] / (S * S);   // heads
    const size_t he = (size_t)nbh * S * S;
    const size_t need = he * sizeof(__bf16) * 5;   // vth,vtl,vtll,r_hi,r_lo
    const size_t kt_bytes = he * sizeof(float);

    if (ws_size >= need) {
        __bf16* vth  = (__bf16*)d_ws;
        __bf16* vtl  = vth + he;
        __bf16* vtll = vtl + he;
        __bf16* rhi  = vtll + he;
        __bf16* rlo  = rhi + he;
        const int nblk = nbh * 4;
        const int swz = (nblk % 8 == 0) ? 1 : 0;
        vsplit_kernel<<<dim3(nbh * 8), NT, 0, stream>>>(v, vth, vtl, vtll);
        qkt_kernel<<<dim3(nblk), NT, 0, stream>>>(q, k, rhi, rlo, swz);
        attn2_kernel<<<dim3(nblk), NT, 0, stream>>>(
            mask, rhi, rlo, vth, vtl, vtll, out, H, swz);
    } else if (ws_size >= kt_bytes) {
        float* kt = (float*)d_ws;
        transpose_k_kernel<<<dim3(nbh * 16), NT, 0, stream>>>(k, kt);
        constexpr int RPB = 16;
        const int grid = nbh * (S / RPB);
        const int swz = (nbh % 8 == 0) ? 1 : 0;
        fused_attn_rpb<RPB><<<dim3(grid), NT, 0, stream>>>(
            q, kt, v, mask, out, nbh, H, swz);
    }
}

// Round 12
// 91.846 us; speedup vs baseline: 3.3852x; 1.0895x over previous
//
#include <hip/hip_runtime.h>
#include <math.h>

namespace {
constexpr int S  = 256;
constexpr int NT = 256;
constexpr float SCALE = 0.0625f;  // 1/sqrt(256)
constexpr int KLD = 264;          // LDS row stride (bf16 elems): 256 + 8 pad
}

typedef __bf16 bf16x4 __attribute__((ext_vector_type(4)));
typedef __bf16 bf16x8 __attribute__((ext_vector_type(8)));
typedef float  f32x4  __attribute__((ext_vector_type(4)));

#define MFMA(a, b, c) __builtin_amdgcn_mfma_f32_16x16x32_bf16((a), (b), (c), 0, 0, 0)

// ===== prep: V^T 3-way bf16 split, FRAGMENT-PACKED (verified round 9/10) =====
// packed idx (per bh): tc*8192 + j*512 + lane*8 + e
//   where d = j*16 + (lane&15), t = tc*32 + (lane>>4)*8 + e
__global__ __launch_bounds__(NT) void vsplit_kernel(
    const float* __restrict__ v,
    __bf16* __restrict__ vth, __bf16* __restrict__ vtl, __bf16* __restrict__ vtll)
{
    __shared__ float tile[32][257];     // [t_local][d]
    const int bh = blockIdx.x >> 3;
    const int tc = blockIdx.x & 7;
    const int tid = threadIdx.x;

    const float* vb = v + (size_t)bh * S * S + (size_t)tc * 32 * S;
    {
        const int c4 = (tid & 63) * 4;
        const int r  = tid >> 6;
        #pragma unroll
        for (int rr = 0; rr < 8; ++rr) {
            const int row = rr * 4 + r;
            const float4 f = *(const float4*)&vb[(size_t)row * S + c4];
            tile[row][c4 + 0] = f.x; tile[row][c4 + 1] = f.y;
            tile[row][c4 + 2] = f.z; tile[row][c4 + 3] = f.w;
        }
    }
    __syncthreads();

    const size_t obase = (size_t)bh * S * S + (size_t)tc * 8192;
    #pragma unroll
    for (int it = 0; it < 4; ++it) {
        const int id  = it * 256 + tid;      // 0..1023
        const int j   = id >> 6;
        const int l4  = (id >> 4) & 3;
        const int l15 = id & 15;
        const int d   = j * 16 + l15;
        const int t0  = l4 * 8;
        bf16x8 hv, lv, llv;
        #pragma unroll
        for (int e = 0; e < 8; ++e) {
            const float x = tile[t0 + e][d];
            const __bf16 hi = (__bf16)x;
            const float  hf = (float)hi;
            const __bf16 lo = (__bf16)(x - hf);
            const float  lf = (float)lo;
            hv[e] = hi; lv[e] = lo; llv[e] = (__bf16)(x - hf - lf);
        }
        const size_t oi = obase + (size_t)id * 8;
        *(bf16x8*)&vth[oi]  = hv;
        *(bf16x8*)&vtl[oi]  = lv;
        *(bf16x8*)&vtll[oi] = llv;
    }
}

// ===== QKT v2: 64s x 64t tiles, one-shot K staging, 1 barrier =====
// block: 256 thr / 4 waves; wave w owns s-rows [s0+16w, s0+16w+16).
// K t-tile rows [t0, t0+64) are CONTIGUOUS in memory -> flat coalesced copy.
__global__ __launch_bounds__(NT, 2) void qkt_kernel(
    const float* __restrict__ q, const float* __restrict__ k,
    __bf16* __restrict__ r_hi, __bf16* __restrict__ r_lo, int swz)
{
    __shared__ __align__(16) __bf16 kh[64 * KLD];
    __shared__ __align__(16) __bf16 kl[64 * KLD];

    const int tid = threadIdx.x;
    const int w = tid >> 6, l = tid & 63, l15 = l & 15, l4 = l >> 4;

    int L = blockIdx.x;
    if (swz) L = (blockIdx.x & 7) * ((int)gridDim.x >> 3) + (blockIdx.x >> 3);
    const int bh = L >> 4;
    const int s0 = ((L >> 2) & 3) << 6;
    const int t0 = (L & 3) << 6;

    const float* qb = q + ((size_t)bh << 16);
    const float* kb = k + ((size_t)bh << 16);

    // ---- stage K tile [t0, t0+64) x 256, hi/lo split, flat coalesced ----
    {
        const float* ksrc = kb + (size_t)t0 * S;    // 64 KB contiguous
        #pragma unroll 4
        for (int it = 0; it < 16; ++it) {
            const int idx = it * 1024 + tid * 4;    // flat fp32 idx in tile
            const float4 f = *(const float4*)&ksrc[idx];
            const float xs[4] = {f.x, f.y, f.z, f.w};
            bf16x4 hv, lv;
            #pragma unroll
            for (int e = 0; e < 4; ++e) {
                const __bf16 hi = (__bf16)xs[e];
                hv[e] = hi; lv[e] = (__bf16)(xs[e] - (float)hi);
            }
            const int row = idx >> 8;
            const int col = idx & 255;
            *(bf16x4*)&kh[row * KLD + col] = hv;
            *(bf16x4*)&kl[row * KLD + col] = lv;
        }
    }

    // ---- Q rows, pre-scaled, hi/lo split (own 16 rows per wave) ----
    bf16x8 qh[8], ql[8];
    {
        const float* qr = qb + (size_t)(s0 + 16 * w + l15) * S;
        #pragma unroll
        for (int kc = 0; kc < 8; ++kc) {
            const float4 f0 = *(const float4*)&qr[kc * 32 + l4 * 8];
            const float4 f1 = *(const float4*)&qr[kc * 32 + l4 * 8 + 4];
            const float xs[8] = {f0.x, f0.y, f0.z, f0.w, f1.x, f1.y, f1.z, f1.w};
            bf16x8 hv, lv;
            #pragma unroll
            for (int e = 0; e < 8; ++e) {
                const float x = xs[e] * SCALE;
                const __bf16 hi = (__bf16)x;
                hv[e] = hi; lv[e] = (__bf16)(x - (float)hi);
            }
            qh[kc] = hv; ql[kc] = lv;
        }
    }
    __syncthreads();   // the ONLY barrier

    // ---- accumulate r tile: 4 t-frags x 8 kc x 3 split passes ----
    f32x4 acc[4];
    #pragma unroll
    for (int j = 0; j < 4; ++j) acc[j] = (f32x4){0.f, 0.f, 0.f, 0.f};

    #pragma unroll
    for (int kc = 0; kc < 8; ++kc) {
        #pragma unroll
        for (int j = 0; j < 4; ++j) {
            const int bo = (j * 16 + l15) * KLD + kc * 32 + l4 * 8;
            const bf16x8 khf = *(const bf16x8*)&kh[bo];
            const bf16x8 klf = *(const bf16x8*)&kl[bo];
            acc[j] = MFMA(qh[kc], khf, acc[j]);
            acc[j] = MFMA(qh[kc], klf, acc[j]);
            acc[j] = MFMA(ql[kc], khf, acc[j]);
        }
    }

    // ---- epilogue: row-major r_hi/r_lo (layout unchanged for attn2) ----
    __bf16* rh_b = r_hi + ((size_t)bh << 16);
    __bf16* rl_b = r_lo + ((size_t)bh << 16);
    #pragma unroll
    for (int j = 0; j < 4; ++j) {
        #pragma unroll
        for (int rr = 0; rr < 4; ++rr) {
            const int row = s0 + 16 * w + l4 * 4 + rr;
            const int t   = t0 + j * 16 + l15;
            const float rv = acc[j][rr];
            const __bf16 hi = (__bf16)rv;
            rh_b[(size_t)row * S + t] = hi;
            rl_b[(size_t)row * S + t] = (__bf16)(rv - (float)hi);
        }
    }
}

// ===== attn2: 64 KB aliased-arena LDS pipeline, 2 blocks/CU (verified r11) =====
#define SRC_OF(sp) ((sp) == 0 ? vth : (sp) == 1 ? vtl : vtll)

#define P2_LOAD(tc)                                                           \
    _Pragma("unroll")                                                         \
    for (int r_ = 0; r_ < 12; ++r_) {                                         \
        const int sp_ = r_ >> 2, qt_ = r_ & 3;                                \
        const __bf16* s_ = SRC_OF(sp_);                                       \
        stg[r_] = *(const bf16x8*)&s_[hb + (size_t)(tc) * 8192 + qt_ * 2048 + tid * 8]; \
    }

#define P2_WRITE()                                                            \
    _Pragma("unroll")                                                         \
    for (int r_ = 0; r_ < 12; ++r_) {                                         \
        const int sp_ = r_ >> 2, qt_ = r_ & 3;                                \
        *(bf16x8*)&arena[sp_ * 8192 + qt_ * 2048 + tid * 8] = stg[r_];        \
    }

#define P3_LOAD(tc)                                                           \
    _Pragma("unroll")                                                         \
    for (int r_ = 0; r_ < 8; ++r_) {                                          \
        const int sp_ = r_ >> 2, qt_ = r_ & 3;                                \
        const __bf16* s_ = SRC_OF(sp_);                                       \
        stg[r_] = *(const bf16x8*)&s_[hb + (size_t)(tc) * 8192 + qt_ * 2048 + tid * 8]; \
    }

#define P3_WRITE()                                                            \
    _Pragma("unroll")                                                         \
    for (int r_ = 0; r_ < 8; ++r_) {                                          \
        const int sp_ = r_ >> 2, qt_ = r_ & 3;                                \
        *(bf16x8*)&arena[16384 + sp_ * 8192 + qt_ * 2048 + tid * 8] = stg[r_];\
    }

__global__ __launch_bounds__(NT, 2) void attn2_kernel(
    const float* __restrict__ mask,
    const __bf16* __restrict__ r_hi, const __bf16* __restrict__ r_lo,
    const __bf16* __restrict__ vth, const __bf16* __restrict__ vtl,
    const __bf16* __restrict__ vtll,
    float* __restrict__ out, int H, int swz)
{
    __shared__ __align__(16) __bf16 arena[32768];   // 64 KB

    const int tid = threadIdx.x;
    const int w = tid >> 6, l = tid & 63, l15 = l & 15, l4 = l >> 4;

    int L = blockIdx.x;
    if (swz) L = (blockIdx.x & 7) * ((int)gridDim.x >> 3) + (blockIdx.x >> 3);
    const int bh = L >> 2;
    const int s0 = (L & 3) << 6;
    const int h  = bh % H;

    const size_t hb = (size_t)bh << 16;
    const float* mbase = mask + ((size_t)h << 16);

    const int arow_g = s0 + 16 * w + l15;
    const __bf16* rh_p = r_hi + hb + (size_t)arow_g * S;
    const __bf16* rl_p = r_lo + hb + (size_t)arow_g * S;
    const float*  m_p  = mbase + (size_t)arow_g * S;

    bf16x8 stg[12];

    // ---- phase 2: acc2 = (mask + r) @ V ----
    f32x4 acc2[16];
    #pragma unroll
    for (int j = 0; j < 16; ++j) acc2[j] = (f32x4){0.f, 0.f, 0.f, 0.f};

    P2_LOAD(0);
    P2_WRITE();
    P2_LOAD(1);
    bf16x8 rhc, rlc; float4 m0c, m1c;
    {
        const int ko_ = l4 * 8;
        rhc = *(const bf16x8*)&rh_p[ko_];
        rlc = *(const bf16x8*)&rl_p[ko_];
        m0c = *(const float4*)&m_p[ko_];
        m1c = *(const float4*)&m_p[ko_ + 4];
    }
    __syncthreads();

    #pragma unroll
    for (int tc = 0; tc < 8; ++tc) {
        bf16x8 rhn, rln; float4 m0n, m1n;
        if (tc < 7) {
            const int ko_ = (tc + 1) * 32 + l4 * 8;
            rhn = *(const bf16x8*)&rh_p[ko_];
            rln = *(const bf16x8*)&rl_p[ko_];
            m0n = *(const float4*)&m_p[ko_];
            m1n = *(const float4*)&m_p[ko_ + 4];
        }
        bf16x8 mf;
        mf[0] = (__bf16)m0c.x; mf[1] = (__bf16)m0c.y;
        mf[2] = (__bf16)m0c.z; mf[3] = (__bf16)m0c.w;
        mf[4] = (__bf16)m1c.x; mf[5] = (__bf16)m1c.y;
        mf[6] = (__bf16)m1c.z; mf[7] = (__bf16)m1c.w;

        #pragma unroll
        for (int j = 0; j < 16; ++j) {
            const int fo = j * 512 + l * 8;      // lane-linear, conflict-free
            const bf16x8 vh  = *(const bf16x8*)&arena[fo];
            const bf16x8 vl  = *(const bf16x8*)&arena[8192 + fo];
            const bf16x8 vll = *(const bf16x8*)&arena[16384 + fo];
            acc2[j] = MFMA(mf,  vh,  acc2[j]);
            acc2[j] = MFMA(mf,  vl,  acc2[j]);
            acc2[j] = MFMA(mf,  vll, acc2[j]);
            acc2[j] = MFMA(rhc, vh,  acc2[j]);
            acc2[j] = MFMA(rhc, vl,  acc2[j]);
            acc2[j] = MFMA(rlc, vh,  acc2[j]);
        }
        __syncthreads();
        if (tc < 7) {
            P2_WRITE();
            if (tc < 6) P2_LOAD(tc + 2);
            rhc = rhn; rlc = rln; m0c = m0n; m1c = m1n;
            __syncthreads();
        }
    }

    P3_LOAD(0);

    // ---- masked fill + row softmax (in-register, per 16-lane group) ----
    #pragma unroll
    for (int rr = 0; rr < 4; ++rr) {
        const int srow = 16 * w + l4 * 4 + rr;
        const float* mrow = mbase + (size_t)(s0 + srow) * S;
        float mx = -3.4e38f;
        #pragma unroll
        for (int j = 0; j < 16; ++j) {
            const float mval = mrow[j * 16 + l15];
            const float a = (mval == 0.0f) ? -1e9f : acc2[j][rr];
            acc2[j][rr] = a;
            mx = fmaxf(mx, a);
        }
        #pragma unroll
        for (int off = 1; off < 16; off <<= 1)
            mx = fmaxf(mx, __shfl_xor(mx, off, 64));
        float sm = 0.f;
        #pragma unroll
        for (int j = 0; j < 16; ++j) {
            const float e = __expf(acc2[j][rr] - mx);
            acc2[j][rr] = e;
            sm += e;
        }
        #pragma unroll
        for (int off = 1; off < 16; off <<= 1)
            sm += __shfl_xor(sm, off, 64);
        const float inv = 1.0f / sm;
        #pragma unroll
        for (int j = 0; j < 16; ++j) {
            const int t = j * 16 + l15;
            arena[((srow << 8) + t) ^ ((srow & 7) << 3)] = (__bf16)(acc2[j][rr] * inv);
        }
    }
    P3_WRITE();
    P3_LOAD(1);
    __syncthreads();

    // ---- phase 3: out = P @ V ----
    f32x4 acc3[16];
    #pragma unroll
    for (int j = 0; j < 16; ++j) acc3[j] = (f32x4){0.f, 0.f, 0.f, 0.f};

    const int prow = 16 * w + l15;
    #pragma unroll
    for (int tc = 0; tc < 8; ++tc) {
        const int pb = ((prow << 8) + tc * 32 + l4 * 8) ^ ((prow & 7) << 3);
        const bf16x8 pa = *(const bf16x8*)&arena[pb];
        #pragma unroll
        for (int j = 0; j < 16; ++j) {
            const int fo = 16384 + j * 512 + l * 8;
            acc3[j] = MFMA(pa, *(const bf16x8*)&arena[fo], acc3[j]);
            acc3[j] = MFMA(pa, *(const bf16x8*)&arena[8192 + fo], acc3[j]);
        }
        __syncthreads();
        if (tc < 7) {
            P3_WRITE();
            if (tc < 6) P3_LOAD(tc + 2);
            __syncthreads();
        }
    }

    float* ob = out + hb + (size_t)s0 * S;
    #pragma unroll
    for (int j = 0; j < 16; ++j) {
        #pragma unroll
        for (int rr = 0; rr < 4; ++rr)
            ob[(size_t)(16 * w + l4 * 4 + rr) * S + j * 16 + l15] = acc3[j][rr];
    }
}

// ================= fallback: fp32 path (verified round 2) =================
__global__ __launch_bounds__(NT) void transpose_k_kernel(
    const float* __restrict__ k, float* __restrict__ kt)
{
    __shared__ float tile[64][65];
    const int tileIdx = blockIdx.x & 15;
    const int bh      = blockIdx.x >> 4;
    const int ti = (tileIdx >> 2) * 64;
    const int tj = (tileIdx & 3) * 64;
    const float* kb = k  + (size_t)bh * S * S;
    float*      ktb = kt + (size_t)bh * S * S;
    const int c  = threadIdx.x & 63;
    const int r4 = threadIdx.x >> 6;
    #pragma unroll
    for (int rr = 0; rr < 64; rr += 4)
        tile[rr + r4][c] = kb[(size_t)(ti + rr + r4) * S + tj + c];
    __syncthreads();
    #pragma unroll
    for (int rr = 0; rr < 64; rr += 4)
        ktb[(size_t)(tj + rr + r4) * S + ti + c] = tile[c][rr + r4];
}

template <int RPB>
__global__ __launch_bounds__(NT) void fused_attn_rpb(
    const float* __restrict__ q, const float* __restrict__ kt,
    const float* __restrict__ v, const float* __restrict__ mask,
    float* __restrict__ out, int nbh, int H, int swizzle)
{
    __shared__ float qT[S][RPB];
    __shared__ float sT[S][RPB];
    __shared__ float redbuf[4][RPB];

    const int tid = threadIdx.x;
    constexpr int NRB = S / RPB;
    int bh, rb;
    if (swizzle) {
        const int xcd  = blockIdx.x & 7;
        const int slot = blockIdx.x >> 3;
        const int hpx  = nbh >> 3;
        bh = xcd * hpx + (slot % hpx);
        rb = slot / hpx;
    } else {
        bh = blockIdx.x / NRB;
        rb = blockIdx.x % NRB;
    }
    const int h  = bh % H;
    const int s0 = rb * RPB;

    const float* qb  = q    + (size_t)bh * S * S;
    const float* ktb = kt   + (size_t)bh * S * S;
    const float* vb  = v    + (size_t)bh * S * S;
    const float* mb  = mask + (size_t)h  * S * S + (size_t)s0 * S;
    float*       ob  = out  + (size_t)bh * S * S + (size_t)s0 * S;

    #pragma unroll
    for (int si = 0; si < RPB; ++si)
        qT[tid][si] = qb[(size_t)(s0 + si) * S + tid];
    __syncthreads();

    {
        float acc[RPB];
        #pragma unroll
        for (int si = 0; si < RPB; ++si) acc[si] = 0.f;
        #pragma unroll 4
        for (int i = 0; i < S; ++i) {
            const float kv = ktb[(size_t)i * S + tid];
            #pragma unroll
            for (int si4 = 0; si4 < RPB; si4 += 4) {
                const float4 qa = *reinterpret_cast<const float4*>(&qT[i][si4]);
                acc[si4+0] = fmaf(qa.x, kv, acc[si4+0]);
                acc[si4+1] = fmaf(qa.y, kv, acc[si4+1]);
                acc[si4+2] = fmaf(qa.z, kv, acc[si4+2]);
                acc[si4+3] = fmaf(qa.w, kv, acc[si4+3]);
            }
        }
        #pragma unroll
        for (int si4 = 0; si4 < RPB; si4 += 4) {
            float4 t4;
            t4.x = fmaf(acc[si4+0], SCALE, mb[(size_t)(si4+0)*S + tid]);
            t4.y = fmaf(acc[si4+1], SCALE, mb[(size_t)(si4+1)*S + tid]);
            t4.z = fmaf(acc[si4+2], SCALE, mb[(size_t)(si4+2)*S + tid]);
            t4.w = fmaf(acc[si4+3], SCALE, mb[(size_t)(si4+3)*S + tid]);
            *reinterpret_cast<float4*>(&sT[tid][si4]) = t4;
        }
    }
    __syncthreads();

    float a1[RPB];
    #pragma unroll
    for (int si = 0; si < RPB; ++si) a1[si] = 0.f;
    #pragma unroll 2
    for (int t = 0; t < S; ++t) {
        const float vv = vb[(size_t)t * S + tid];
        #pragma unroll
        for (int si4 = 0; si4 < RPB; si4 += 4) {
            const float4 pa = *reinterpret_cast<const float4*>(&sT[t][si4]);
            a1[si4+0] = fmaf(pa.x, vv, a1[si4+0]);
            a1[si4+1] = fmaf(pa.y, vv, a1[si4+1]);
            a1[si4+2] = fmaf(pa.z, vv, a1[si4+2]);
            a1[si4+3] = fmaf(pa.w, vv, a1[si4+3]);
        }
    }
    #pragma unroll
    for (int si = 0; si < RPB; ++si)
        if (mb[(size_t)si * S + tid] == 0.0f) a1[si] = -1e9f;

    const int lane = tid & 63;
    const int wv   = tid >> 6;
    #pragma unroll
    for (int si = 0; si < RPB; ++si) {
        float m = a1[si];
        #pragma unroll
        for (int off = 32; off > 0; off >>= 1)
            m = fmaxf(m, __shfl_down(m, off, 64));
        if (lane == 0) redbuf[wv][si] = m;
    }
    __syncthreads();
    float e[RPB];
    #pragma unroll
    for (int si = 0; si < RPB; ++si) {
        const float m = fmaxf(fmaxf(redbuf[0][si], redbuf[1][si]),
                              fmaxf(redbuf[2][si], redbuf[3][si]));
        e[si] = __expf(a1[si] - m);
    }
    __syncthreads();
    #pragma unroll
    for (int si = 0; si < RPB; ++si) {
        float sm = e[si];
        #pragma unroll
        for (int off = 32; off > 0; off >>= 1)
            sm += __shfl_down(sm, off, 64);
        if (lane == 0) redbuf[wv][si] = sm;
    }
    __syncthreads();
    #pragma unroll
    for (int si4 = 0; si4 < RPB; si4 += 4) {
        float4 t4;
        #pragma unroll
        for (int jj = 0; jj < 4; ++jj) {
            const int si = si4 + jj;
            const float sm = redbuf[0][si] + redbuf[1][si] +
                             redbuf[2][si] + redbuf[3][si];
            (&t4.x)[jj] = e[si] / sm;
        }
        *reinterpret_cast<float4*>(&sT[tid][si4]) = t4;
    }
    __syncthreads();

    float o[RPB];
    #pragma unroll
    for (int si = 0; si < RPB; ++si) o[si] = 0.f;
    #pragma unroll 2
    for (int t = 0; t < S; ++t) {
        const float vv = vb[(size_t)t * S + tid];
        #pragma unroll
        for (int si4 = 0; si4 < RPB; si4 += 4) {
            const float4 pa = *reinterpret_cast<const float4*>(&sT[t][si4]);
            o[si4+0] = fmaf(pa.x, vv, o[si4+0]);
            o[si4+1] = fmaf(pa.y, vv, o[si4+1]);
            o[si4+2] = fmaf(pa.z, vv, o[si4+2]);
            o[si4+3] = fmaf(pa.w, vv, o[si4+3]);
        }
    }
    #pragma unroll
    for (int si = 0; si < RPB; ++si)
        ob[(size_t)si * S + tid] = o[si];
}

extern "C" void kernel_launch(void* const* d_in, const int* in_sizes, int n_in,
                              void* d_out, int out_size, void* d_ws, size_t ws_size,
                              hipStream_t stream) {
    const float* q    = (const float*)d_in[0];
    const float* k    = (const float*)d_in[1];
    const float* v    = (const float*)d_in[2];
    const float* mask = (const float*)d_in[3];
    float* out = (float*)d_out;

    const int nbh = in_sizes[0] / (S * S);   // B*H
    const int H   = in_sizes[3] / (S * S);   // heads
    const size_t he = (size_t)nbh * S * S;
    const size_t need = he * sizeof(__bf16) * 5;   // vth,vtl,vtll,r_hi,r_lo
    const size_t kt_bytes = he * sizeof(float);

    if (ws_size >= need) {
        __bf16* vth  = (__bf16*)d_ws;
        __bf16* vtl  = vth + he;
        __bf16* vtll = vtl + he;
        __bf16* rhi  = vtll + he;
        __bf16* rlo  = rhi + he;
        const int nblk_q = nbh * 16;
        const int nblk_a = nbh * 4;
        const int swzq = (nblk_q % 8 == 0) ? 1 : 0;
        const int swza = (nblk_a % 8 == 0) ? 1 : 0;
        vsplit_kernel<<<dim3(nbh * 8), NT, 0, stream>>>(v, vth, vtl, vtll);
        qkt_kernel<<<dim3(nblk_q), NT, 0, stream>>>(q, k, rhi, rlo, swzq);
        attn2_kernel<<<dim3(nblk_a), NT, 0, stream>>>(
            mask, rhi, rlo, vth, vtl, vtll, out, H, swza);
    } else if (ws_size >= kt_bytes) {
        float* kt = (float*)d_ws;
        transpose_k_kernel<<<dim3(nbh * 16), NT, 0, stream>>>(k, kt);
        constexpr int RPB = 16;
        const int grid = nbh * (S / RPB);
        const int swz = (nbh % 8 == 0) ? 1 : 0;
        fused_attn_rpb<RPB><<<dim3(grid), NT, 0, stream>>>(
            q, kt, v, mask, out, nbh, H, swz);
    }
}

// Round 13
// 85.725 us; speedup vs baseline: 3.6269x; 1.0714x over previous
//
#include <hip/hip_runtime.h>
#include <math.h>

namespace {
constexpr int S  = 256;
constexpr int NT = 256;
constexpr float SCALE = 0.0625f;  // 1/sqrt(256)
constexpr int KLD = 264;          // qkt LDS row stride (bf16): 256 + 8 pad
}

typedef __bf16 bf16x4 __attribute__((ext_vector_type(4)));
typedef __bf16 bf16x8 __attribute__((ext_vector_type(8)));
typedef float  f32x4  __attribute__((ext_vector_type(4)));

#define MFMA(a, b, c) __builtin_amdgcn_mfma_f32_16x16x32_bf16((a), (b), (c), 0, 0, 0)

// ===== prep: fused {qkt, vsplit} — roles interleaved via blockIdx%3 =====
// role<2: QKT 64s x 64t tile (verified r12);  role==2: V^T 3-way split (r9).
__global__ __launch_bounds__(NT, 2) void prep_kernel(
    const float* __restrict__ q, const float* __restrict__ k,
    const float* __restrict__ v,
    __bf16* __restrict__ vth, __bf16* __restrict__ vtl, __bf16* __restrict__ vtll,
    __bf16* __restrict__ r_hi, __bf16* __restrict__ r_lo,
    int nbh, int swzq)
{
    __shared__ __align__(16) unsigned char lds_arena[64 * KLD * 2 * 2];  // 67.6 KB

    const int tid  = threadIdx.x;
    const int trio = blockIdx.x / 3;
    const int role = blockIdx.x % 3;

    if (role < 2) {
        // ================= QKT role =================
        __bf16* kh = (__bf16*)lds_arena;
        __bf16* kl = kh + 64 * KLD;

        const int w = tid >> 6, l = tid & 63, l15 = l & 15, l4 = l >> 4;

        int L = trio * 2 + role;                 // [0, nbh*16)
        if (swzq) {
            const int n = nbh * 16;
            L = (L & 7) * (n >> 3) + (L >> 3);
        }
        const int bh = L >> 4;
        const int s0 = ((L >> 2) & 3) << 6;
        const int t0 = (L & 3) << 6;

        const float* qb = q + ((size_t)bh << 16);
        const float* kb = k + ((size_t)bh << 16);

        // stage K tile [t0, t0+64) x 256, hi/lo split, flat coalesced
        {
            const float* ksrc = kb + (size_t)t0 * S;    // 64 KB contiguous
            #pragma unroll 4
            for (int it = 0; it < 16; ++it) {
                const int idx = it * 1024 + tid * 4;
                const float4 f = *(const float4*)&ksrc[idx];
                const float xs[4] = {f.x, f.y, f.z, f.w};
                bf16x4 hv, lv;
                #pragma unroll
                for (int e = 0; e < 4; ++e) {
                    const __bf16 hi = (__bf16)xs[e];
                    hv[e] = hi; lv[e] = (__bf16)(xs[e] - (float)hi);
                }
                const int row = idx >> 8;
                const int col = idx & 255;
                *(bf16x4*)&kh[row * KLD + col] = hv;
                *(bf16x4*)&kl[row * KLD + col] = lv;
            }
        }

        // Q rows, pre-scaled, hi/lo split
        bf16x8 qh[8], ql[8];
        {
            const float* qr = qb + (size_t)(s0 + 16 * w + l15) * S;
            #pragma unroll
            for (int kc = 0; kc < 8; ++kc) {
                const float4 f0 = *(const float4*)&qr[kc * 32 + l4 * 8];
                const float4 f1 = *(const float4*)&qr[kc * 32 + l4 * 8 + 4];
                const float xs[8] = {f0.x, f0.y, f0.z, f0.w, f1.x, f1.y, f1.z, f1.w};
                bf16x8 hv, lv;
                #pragma unroll
                for (int e = 0; e < 8; ++e) {
                    const float x = xs[e] * SCALE;
                    const __bf16 hi = (__bf16)x;
                    hv[e] = hi; lv[e] = (__bf16)(x - (float)hi);
                }
                qh[kc] = hv; ql[kc] = lv;
            }
        }
        __syncthreads();   // the only barrier

        f32x4 acc[4];
        #pragma unroll
        for (int j = 0; j < 4; ++j) acc[j] = (f32x4){0.f, 0.f, 0.f, 0.f};

        #pragma unroll
        for (int kc = 0; kc < 8; ++kc) {
            #pragma unroll
            for (int j = 0; j < 4; ++j) {
                const int bo = (j * 16 + l15) * KLD + kc * 32 + l4 * 8;
                const bf16x8 khf = *(const bf16x8*)&kh[bo];
                const bf16x8 klf = *(const bf16x8*)&kl[bo];
                acc[j] = MFMA(qh[kc], khf, acc[j]);
                acc[j] = MFMA(qh[kc], klf, acc[j]);
                acc[j] = MFMA(ql[kc], khf, acc[j]);
            }
        }

        __bf16* rh_b = r_hi + ((size_t)bh << 16);
        __bf16* rl_b = r_lo + ((size_t)bh << 16);
        #pragma unroll
        for (int j = 0; j < 4; ++j) {
            #pragma unroll
            for (int rr = 0; rr < 4; ++rr) {
                const int row = s0 + 16 * w + l4 * 4 + rr;
                const int t   = t0 + j * 16 + l15;
                const float rv = acc[j][rr];
                const __bf16 hi = (__bf16)rv;
                rh_b[(size_t)row * S + t] = hi;
                rl_b[(size_t)row * S + t] = (__bf16)(rv - (float)hi);
            }
        }
    } else {
        // ================= VSPLIT role =================
        float (*tile)[257] = (float(*)[257])lds_arena;   // 32 x 257 fp32 (33 KB)

        const int vi = trio;                  // [0, nbh*8)
        const int bh = vi >> 3;
        const int tc = vi & 7;

        const float* vb = v + (size_t)bh * S * S + (size_t)tc * 32 * S;
        {
            const int c4 = (tid & 63) * 4;
            const int r  = tid >> 6;
            #pragma unroll
            for (int rr = 0; rr < 8; ++rr) {
                const int row = rr * 4 + r;
                const float4 f = *(const float4*)&vb[(size_t)row * S + c4];
                tile[row][c4 + 0] = f.x; tile[row][c4 + 1] = f.y;
                tile[row][c4 + 2] = f.z; tile[row][c4 + 3] = f.w;
            }
        }
        __syncthreads();

        const size_t obase = (size_t)bh * S * S + (size_t)tc * 8192;
        #pragma unroll
        for (int it = 0; it < 4; ++it) {
            const int id  = it * 256 + tid;      // 0..1023
            const int j   = id >> 6;
            const int l4  = (id >> 4) & 3;
            const int l15 = id & 15;
            const int d   = j * 16 + l15;
            const int t0  = l4 * 8;
            bf16x8 hv, lv, llv;
            #pragma unroll
            for (int e = 0; e < 8; ++e) {
                const float x = tile[t0 + e][d];
                const __bf16 hi = (__bf16)x;
                const float  hf = (float)hi;
                const __bf16 lo = (__bf16)(x - hf);
                const float  lf = (float)lo;
                hv[e] = hi; lv[e] = lo; llv[e] = (__bf16)(x - hf - lf);
            }
            const size_t oi = obase + (size_t)id * 8;
            *(bf16x8*)&vth[oi]  = hv;
            *(bf16x8*)&vtl[oi]  = lv;
            *(bf16x8*)&vtll[oi] = llv;
        }
    }
}

// ===== attn2: 64 KB aliased-arena LDS pipeline, 2 blocks/CU (verified r11/12) =====
#define SRC_OF(sp) ((sp) == 0 ? vth : (sp) == 1 ? vtl : vtll)

#define P2_LOAD(tc)                                                           \
    _Pragma("unroll")                                                         \
    for (int r_ = 0; r_ < 12; ++r_) {                                         \
        const int sp_ = r_ >> 2, qt_ = r_ & 3;                                \
        const __bf16* s_ = SRC_OF(sp_);                                       \
        stg[r_] = *(const bf16x8*)&s_[hb + (size_t)(tc) * 8192 + qt_ * 2048 + tid * 8]; \
    }

#define P2_WRITE()                                                            \
    _Pragma("unroll")                                                         \
    for (int r_ = 0; r_ < 12; ++r_) {                                         \
        const int sp_ = r_ >> 2, qt_ = r_ & 3;                                \
        *(bf16x8*)&arena[sp_ * 8192 + qt_ * 2048 + tid * 8] = stg[r_];        \
    }

#define P3_LOAD(tc)                                                           \
    _Pragma("unroll")                                                         \
    for (int r_ = 0; r_ < 8; ++r_) {                                          \
        const int sp_ = r_ >> 2, qt_ = r_ & 3;                                \
        const __bf16* s_ = SRC_OF(sp_);                                       \
        stg[r_] = *(const bf16x8*)&s_[hb + (size_t)(tc) * 8192 + qt_ * 2048 + tid * 8]; \
    }

#define P3_WRITE()                                                            \
    _Pragma("unroll")                                                         \
    for (int r_ = 0; r_ < 8; ++r_) {                                          \
        const int sp_ = r_ >> 2, qt_ = r_ & 3;                                \
        *(bf16x8*)&arena[16384 + sp_ * 8192 + qt_ * 2048 + tid * 8] = stg[r_];\
    }

__global__ __launch_bounds__(NT, 2) void attn2_kernel(
    const float* __restrict__ mask,
    const __bf16* __restrict__ r_hi, const __bf16* __restrict__ r_lo,
    const __bf16* __restrict__ vth, const __bf16* __restrict__ vtl,
    const __bf16* __restrict__ vtll,
    float* __restrict__ out, int H, int swz)
{
    __shared__ __align__(16) __bf16 arena[32768];   // 64 KB

    const int tid = threadIdx.x;
    const int w = tid >> 6, l = tid & 63, l15 = l & 15, l4 = l >> 4;

    int L = blockIdx.x;
    if (swz) L = (blockIdx.x & 7) * ((int)gridDim.x >> 3) + (blockIdx.x >> 3);
    const int bh = L >> 2;
    const int s0 = (L & 3) << 6;
    const int h  = bh % H;

    const size_t hb = (size_t)bh << 16;
    const float* mbase = mask + ((size_t)h << 16);

    const int arow_g = s0 + 16 * w + l15;
    const __bf16* rh_p = r_hi + hb + (size_t)arow_g * S;
    const __bf16* rl_p = r_lo + hb + (size_t)arow_g * S;
    const float*  m_p  = mbase + (size_t)arow_g * S;

    bf16x8 stg[12];

    // ---- phase 2: acc2 = (mask + r) @ V ----
    f32x4 acc2[16];
    #pragma unroll
    for (int j = 0; j < 16; ++j) acc2[j] = (f32x4){0.f, 0.f, 0.f, 0.f};

    P2_LOAD(0);
    P2_WRITE();
    P2_LOAD(1);
    bf16x8 rhc, rlc; float4 m0c, m1c;
    {
        const int ko_ = l4 * 8;
        rhc = *(const bf16x8*)&rh_p[ko_];
        rlc = *(const bf16x8*)&rl_p[ko_];
        m0c = *(const float4*)&m_p[ko_];
        m1c = *(const float4*)&m_p[ko_ + 4];
    }
    __syncthreads();

    #pragma unroll
    for (int tc = 0; tc < 8; ++tc) {
        bf16x8 rhn, rln; float4 m0n, m1n;
        if (tc < 7) {
            const int ko_ = (tc + 1) * 32 + l4 * 8;
            rhn = *(const bf16x8*)&rh_p[ko_];
            rln = *(const bf16x8*)&rl_p[ko_];
            m0n = *(const float4*)&m_p[ko_];
            m1n = *(const float4*)&m_p[ko_ + 4];
        }
        bf16x8 mf;
        mf[0] = (__bf16)m0c.x; mf[1] = (__bf16)m0c.y;
        mf[2] = (__bf16)m0c.z; mf[3] = (__bf16)m0c.w;
        mf[4] = (__bf16)m1c.x; mf[5] = (__bf16)m1c.y;
        mf[6] = (__bf16)m1c.z; mf[7] = (__bf16)m1c.w;

        __builtin_amdgcn_s_setprio(1);
        #pragma unroll
        for (int j = 0; j < 16; ++j) {
            const int fo = j * 512 + l * 8;      // lane-linear, conflict-free
            const bf16x8 vh  = *(const bf16x8*)&arena[fo];
            const bf16x8 vl  = *(const bf16x8*)&arena[8192 + fo];
            const bf16x8 vll = *(const bf16x8*)&arena[16384 + fo];
            acc2[j] = MFMA(mf,  vh,  acc2[j]);
            acc2[j] = MFMA(mf,  vl,  acc2[j]);
            acc2[j] = MFMA(mf,  vll, acc2[j]);
            acc2[j] = MFMA(rhc, vh,  acc2[j]);
            acc2[j] = MFMA(rhc, vl,  acc2[j]);
            acc2[j] = MFMA(rlc, vh,  acc2[j]);
        }
        __builtin_amdgcn_s_setprio(0);
        __syncthreads();
        if (tc < 7) {
            P2_WRITE();
            if (tc < 6) P2_LOAD(tc + 2);
            rhc = rhn; rlc = rln; m0c = m0n; m1c = m1n;
            __syncthreads();
        }
    }

    P3_LOAD(0);

    // ---- masked fill + row softmax (in-register, per 16-lane group) ----
    #pragma unroll
    for (int rr = 0; rr < 4; ++rr) {
        const int srow = 16 * w + l4 * 4 + rr;
        const float* mrow = mbase + (size_t)(s0 + srow) * S;
        float mx = -3.4e38f;
        #pragma unroll
        for (int j = 0; j < 16; ++j) {
            const float mval = mrow[j * 16 + l15];
            const float a = (mval == 0.0f) ? -1e9f : acc2[j][rr];
            acc2[j][rr] = a;
            mx = fmaxf(mx, a);
        }
        #pragma unroll
        for (int off = 1; off < 16; off <<= 1)
            mx = fmaxf(mx, __shfl_xor(mx, off, 64));
        float sm = 0.f;
        #pragma unroll
        for (int j = 0; j < 16; ++j) {
            const float e = __expf(acc2[j][rr] - mx);
            acc2[j][rr] = e;
            sm += e;
        }
        #pragma unroll
        for (int off = 1; off < 16; off <<= 1)
            sm += __shfl_xor(sm, off, 64);
        const float inv = 1.0f / sm;
        #pragma unroll
        for (int j = 0; j < 16; ++j) {
            const int t = j * 16 + l15;
            arena[((srow << 8) + t) ^ ((srow & 7) << 3)] = (__bf16)(acc2[j][rr] * inv);
        }
    }
    P3_WRITE();
    P3_LOAD(1);
    __syncthreads();

    // ---- phase 3: out = P @ V ----
    f32x4 acc3[16];
    #pragma unroll
    for (int j = 0; j < 16; ++j) acc3[j] = (f32x4){0.f, 0.f, 0.f, 0.f};

    const int prow = 16 * w + l15;
    #pragma unroll
    for (int tc = 0; tc < 8; ++tc) {
        const int pb = ((prow << 8) + tc * 32 + l4 * 8) ^ ((prow & 7) << 3);
        const bf16x8 pa = *(const bf16x8*)&arena[pb];
        __builtin_amdgcn_s_setprio(1);
        #pragma unroll
        for (int j = 0; j < 16; ++j) {
            const int fo = 16384 + j * 512 + l * 8;
            acc3[j] = MFMA(pa, *(const bf16x8*)&arena[fo], acc3[j]);
            acc3[j] = MFMA(pa, *(const bf16x8*)&arena[8192 + fo], acc3[j]);
        }
        __builtin_amdgcn_s_setprio(0);
        __syncthreads();
        if (tc < 7) {
            P3_WRITE();
            if (tc < 6) P3_LOAD(tc + 2);
            __syncthreads();
        }
    }

    float* ob = out + hb + (size_t)s0 * S;
    #pragma unroll
    for (int j = 0; j < 16; ++j) {
        #pragma unroll
        for (int rr = 0; rr < 4; ++rr)
            ob[(size_t)(16 * w + l4 * 4 + rr) * S + j * 16 + l15] = acc3[j][rr];
    }
}

// ================= fallback: fp32 path (verified round 2) =================
__global__ __launch_bounds__(NT) void transpose_k_kernel(
    const float* __restrict__ k, float* __restrict__ kt)
{
    __shared__ float tile[64][65];
    const int tileIdx = blockIdx.x & 15;
    const int bh      = blockIdx.x >> 4;
    const int ti = (tileIdx >> 2) * 64;
    const int tj = (tileIdx & 3) * 64;
    const float* kb = k  + (size_t)bh * S * S;
    float*      ktb = kt + (size_t)bh * S * S;
    const int c  = threadIdx.x & 63;
    const int r4 = threadIdx.x >> 6;
    #pragma unroll
    for (int rr = 0; rr < 64; rr += 4)
        tile[rr + r4][c] = kb[(size_t)(ti + rr + r4) * S + tj + c];
    __syncthreads();
    #pragma unroll
    for (int rr = 0; rr < 64; rr += 4)
        ktb[(size_t)(tj + rr + r4) * S + ti + c] = tile[c][rr + r4];
}

template <int RPB>
__global__ __launch_bounds__(NT) void fused_attn_rpb(
    const float* __restrict__ q, const float* __restrict__ kt,
    const float* __restrict__ v, const float* __restrict__ mask,
    float* __restrict__ out, int nbh, int H, int swizzle)
{
    __shared__ float qT[S][RPB];
    __shared__ float sT[S][RPB];
    __shared__ float redbuf[4][RPB];

    const int tid = threadIdx.x;
    constexpr int NRB = S / RPB;
    int bh, rb;
    if (swizzle) {
        const int xcd  = blockIdx.x & 7;
        const int slot = blockIdx.x >> 3;
        const int hpx  = nbh >> 3;
        bh = xcd * hpx + (slot % hpx);
        rb = slot / hpx;
    } else {
        bh = blockIdx.x / NRB;
        rb = blockIdx.x % NRB;
    }
    const int h  = bh % H;
    const int s0 = rb * RPB;

    const float* qb  = q    + (size_t)bh * S * S;
    const float* ktb = kt   + (size_t)bh * S * S;
    const float* vb  = v    + (size_t)bh * S * S;
    const float* mb  = mask + (size_t)h  * S * S + (size_t)s0 * S;
    float*       ob  = out  + (size_t)bh * S * S + (size_t)s0 * S;

    #pragma unroll
    for (int si = 0; si < RPB; ++si)
        qT[tid][si] = qb[(size_t)(s0 + si) * S + tid];
    __syncthreads();

    {
        float acc[RPB];
        #pragma unroll
        for (int si = 0; si < RPB; ++si) acc[si] = 0.f;
        #pragma unroll 4
        for (int i = 0; i < S; ++i) {
            const float kv = ktb[(size_t)i * S + tid];
            #pragma unroll
            for (int si4 = 0; si4 < RPB; si4 += 4) {
                const float4 qa = *reinterpret_cast<const float4*>(&qT[i][si4]);
                acc[si4+0] = fmaf(qa.x, kv, acc[si4+0]);
                acc[si4+1] = fmaf(qa.y, kv, acc[si4+1]);
                acc[si4+2] = fmaf(qa.z, kv, acc[si4+2]);
                acc[si4+3] = fmaf(qa.w, kv, acc[si4+3]);
            }
        }
        #pragma unroll
        for (int si4 = 0; si4 < RPB; si4 += 4) {
            float4 t4;
            t4.x = fmaf(acc[si4+0], SCALE, mb[(size_t)(si4+0)*S + tid]);
            t4.y = fmaf(acc[si4+1], SCALE, mb[(size_t)(si4+1)*S + tid]);
            t4.z = fmaf(acc[si4+2], SCALE, mb[(size_t)(si4+2)*S + tid]);
            t4.w = fmaf(acc[si4+3], SCALE, mb[(size_t)(si4+3)*S + tid]);
            *reinterpret_cast<float4*>(&sT[tid][si4]) = t4;
        }
    }
    __syncthreads();

    float a1[RPB];
    #pragma unroll
    for (int si = 0; si < RPB; ++si) a1[si] = 0.f;
    #pragma unroll 2
    for (int t = 0; t < S; ++t) {
        const float vv = vb[(size_t)t * S + tid];
        #pragma unroll
        for (int si4 = 0; si4 < RPB; si4 += 4) {
            const float4 pa = *reinterpret_cast<const float4*>(&sT[t][si4]);
            a1[si4+0] = fmaf(pa.x, vv, a1[si4+0]);
            a1[si4+1] = fmaf(pa.y, vv, a1[si4+1]);
            a1[si4+2] = fmaf(pa.z, vv, a1[si4+2]);
            a1[si4+3] = fmaf(pa.w, vv, a1[si4+3]);
        }
    }
    #pragma unroll
    for (int si = 0; si < RPB; ++si)
        if (mb[(size_t)si * S + tid] == 0.0f) a1[si] = -1e9f;

    const int lane = tid & 63;
    const int wv   = tid >> 6;
    #pragma unroll
    for (int si = 0; si < RPB; ++si) {
        float m = a1[si];
        #pragma unroll
        for (int off = 32; off > 0; off >>= 1)
            m = fmaxf(m, __shfl_down(m, off, 64));
        if (lane == 0) redbuf[wv][si] = m;
    }
    __syncthreads();
    float e[RPB];
    #pragma unroll
    for (int si = 0; si < RPB; ++si) {
        const float m = fmaxf(fmaxf(redbuf[0][si], redbuf[1][si]),
                              fmaxf(redbuf[2][si], redbuf[3][si]));
        e[si] = __expf(a1[si] - m);
    }
    __syncthreads();
    #pragma unroll
    for (int si = 0; si < RPB; ++si) {
        float sm = e[si];
        #pragma unroll
        for (int off = 32; off > 0; off >>= 1)
            sm += __shfl_down(sm, off, 64);
        if (lane == 0) redbuf[wv][si] = sm;
    }
    __syncthreads();
    #pragma unroll
    for (int si4 = 0; si4 < RPB; si4 += 4) {
        float4 t4;
        #pragma unroll
        for (int jj = 0; jj < 4; ++jj) {
            const int si = si4 + jj;
            const float sm = redbuf[0][si] + redbuf[1][si] +
                             redbuf[2][si] + redbuf[3][si];
            (&t4.x)[jj] = e[si] / sm;
        }
        *reinterpret_cast<float4*>(&sT[tid][si4]) = t4;
    }
    __syncthreads();

    float o[RPB];
    #pragma unroll
    for (int si = 0; si < RPB; ++si) o[si] = 0.f;
    #pragma unroll 2
    for (int t = 0; t < S; ++t) {
        const float vv = vb[(size_t)t * S + tid];
        #pragma unroll
        for (int si4 = 0; si4 < RPB; si4 += 4) {
            const float4 pa = *reinterpret_cast<const float4*>(&sT[t][si4]);
            o[si4+0] = fmaf(pa.x, vv, o[si4+0]);
            o[si4+1] = fmaf(pa.y, vv, o[si4+1]);
            o[si4+2] = fmaf(pa.z, vv, o[si4+2]);
            o[si4+3] = fmaf(pa.w, vv, o[si4+3]);
        }
    }
    #pragma unroll
    for (int si = 0; si < RPB; ++si)
        ob[(size_t)si * S + tid] = o[si];
}

extern "C" void kernel_launch(void* const* d_in, const int* in_sizes, int n_in,
                              void* d_out, int out_size, void* d_ws, size_t ws_size,
                              hipStream_t stream) {
    const float* q    = (const float*)d_in[0];
    const float* k    = (const float*)d_in[1];
    const float* v    = (const float*)d_in[2];
    const float* mask = (const float*)d_in[3];
    float* out = (float*)d_out;

    const int nbh = in_sizes[0] / (S * S);   // B*H
    const int H   = in_sizes[3] / (S * S);   // heads
    const size_t he = (size_t)nbh * S * S;
    const size_t need = he * sizeof(__bf16) * 5;   // vth,vtl,vtll,r_hi,r_lo
    const size_t kt_bytes = he * sizeof(float);

    if (ws_size >= need) {
        __bf16* vth  = (__bf16*)d_ws;
        __bf16* vtl  = vth + he;
        __bf16* vtll = vtl + he;
        __bf16* rhi  = vtll + he;
        __bf16* rlo  = rhi + he;
        const int nblk_q = nbh * 16;
        const int nblk_a = nbh * 4;
        const int swzq = (nblk_q % 8 == 0) ? 1 : 0;
        const int swza = (nblk_a % 8 == 0) ? 1 : 0;
        prep_kernel<<<dim3(nbh * 24), NT, 0, stream>>>(
            q, k, v, vth, vtl, vtll, rhi, rlo, nbh, swzq);
        attn2_kernel<<<dim3(nblk_a), NT, 0, stream>>>(
            mask, rhi, rlo, vth, vtl, vtll, out, H, swza);
    } else if (ws_size >= kt_bytes) {
        float* kt = (float*)d_ws;
        transpose_k_kernel<<<dim3(nbh * 16), NT, 0, stream>>>(k, kt);
        constexpr int RPB = 16;
        const int grid = nbh * (S / RPB);
        const int swz = (nbh % 8 == 0) ? 1 : 0;
        fused_attn_rpb<RPB><<<dim3(grid), NT, 0, stream>>>(
            q, kt, v, mask, out, nbh, H, swz);
    }
}